// Round 6
// baseline (541.082 us; speedup 1.0000x reference)
//
#include <hip/hip_runtime.h>
#include <math.h>

#define N_NODES 50000
#define F_IN    512
#define H1      8
#define C1      8
#define D1      64    // H1*C1
#define OUT_C   128
#define NEG     0.2f

#define SCHUNK  256
#define SNBLK   ((N_NODES + SCHUNK - 1)/SCHUNK)   // 196

using bf16x8 = __attribute__((ext_vector_type(8))) short;
using f32x4  = __attribute__((ext_vector_type(4))) float;
typedef unsigned short u16;
typedef unsigned int   u32;

__device__ __forceinline__ float leaky(float x){
    return fmaxf(x, 0.f) + NEG * fminf(x, 0.f);
}
__device__ __forceinline__ u16 f2bf(float f){           // RNE
    u32 u = __float_as_uint(f);
    u32 r = u + 0x7FFF + ((u>>16)&1);
    return (u16)(r>>16);
}
__device__ __forceinline__ float bf2f(u16 h){ return __uint_as_float(((u32)h)<<16); }

// ---------------------------------------------------------------- counts (self-loop => start at 1)
__global__ void k_zero_cnt(int* cnt){
    int i = blockIdx.x*blockDim.x + threadIdx.x;
    if (i < N_NODES) cnt[i] = 1;
}

__global__ void k_hist(const int* __restrict__ dst_a, int E, int* cnt){
    int i = blockIdx.x*blockDim.x + threadIdx.x;
    if (i >= E) return;
    atomicAdd(cnt + dst_a[i], 1);
}

// ---------------------------------------------------------------- 3-phase scan
__global__ __launch_bounds__(256) void k_scanA(const int* __restrict__ cnt, int* bsum){
    __shared__ int sm[256];
    int idx = blockIdx.x*256 + threadIdx.x;
    int v = (idx < N_NODES) ? cnt[idx] : 0;
    sm[threadIdx.x] = v; __syncthreads();
    for (int off=128; off>0; off>>=1){
        if (threadIdx.x < off) sm[threadIdx.x] += sm[threadIdx.x+off];
        __syncthreads();
    }
    if (threadIdx.x==0) bsum[blockIdx.x] = sm[0];
}

__global__ __launch_bounds__(256) void k_scanB(const int* __restrict__ bsum, int* boff, int* rowptr){
    __shared__ int sm[256];
    int t = threadIdx.x;
    int v = (t < SNBLK) ? bsum[t] : 0;
    sm[t]=v; __syncthreads();
    for (int off=1; off<256; off<<=1){
        int u = (t>=off)? sm[t-off] : 0;
        __syncthreads();
        sm[t]+=u; __syncthreads();
    }
    if (t < SNBLK) boff[t] = sm[t] - v;       // exclusive
    if (t==255) rowptr[N_NODES] = sm[255];    // total = E + N
}

__global__ __launch_bounds__(256) void k_scanC(const int* __restrict__ cnt, const int* __restrict__ boff,
                                               int* rowptr, int* cur){
    __shared__ int sm[256];
    int idx = blockIdx.x*256 + threadIdx.x;
    int t = threadIdx.x;
    int v = (idx<N_NODES)? cnt[idx] : 0;
    sm[t]=v; __syncthreads();
    for (int off=1; off<256; off<<=1){
        int u = (t>=off)? sm[t-off] : 0;
        __syncthreads();
        sm[t]+=u; __syncthreads();
    }
    if (idx<N_NODES){
        int ex = boff[blockIdx.x] + sm[t] - v;
        rowptr[idx]=ex; cur[idx]=ex;
    }
}

// ---------------------------------------------------------------- scatter: one 4B store per edge (src only)
__global__ void k_scatter(const int* __restrict__ src_a, const int* __restrict__ dst_a,
                          int E, int* cur, int* srcs){
    int i = blockIdx.x*blockDim.x + threadIdx.x;
    int ET = E + N_NODES;
    if (i >= ET) return;
    int s, d;
    if (i < E){ s = src_a[i]; d = dst_a[i]; }
    else      { s = d = i - E; }
    int pos = atomicAdd(cur + d, 1);
    srcs[pos] = s;
}

// ---------------------------------------------------------------- W1 split/transpose: whiT/wloT [64 col][512 k] bf16
__global__ void k_cvtW(const float* __restrict__ W1, u16* __restrict__ whiT, u16* __restrict__ wloT){
    int i = blockIdx.x*blockDim.x + threadIdx.x;   // 0..32767
    if (i >= F_IN*D1) return;
    int k = i >> 6, col = i & 63;
    float v = W1[i];
    u16 hi = f2bf(v);
    float lo = v - bf2f(hi);
    whiT[col*F_IN + k] = hi;
    wloT[col*F_IN + k] = f2bf(lo);
}

// ---------------------------------------------------------------- W2 split/transpose: [128 col][64 k] bf16
__global__ void k_cvtW2(const float* __restrict__ W2, u16* __restrict__ w2hiT, u16* __restrict__ w2loT){
    int i = blockIdx.x*blockDim.x + threadIdx.x;   // 0..8191
    if (i >= D1*OUT_C) return;
    int k = i >> 7, col = i & 127;
    float v = W2[i];
    u16 hi = f2bf(v);
    float lo = v - bf2f(hi);
    w2hiT[col*D1 + k] = hi;
    w2loT[col*D1 + k] = f2bf(lo);
}

// ---------------------------------------------------------------- GEMM1 via MFMA (split-bf16, f32-accurate)
// block: 256 thr = 4 waves; tile 64 nodes x 64 cols; K step 64
__global__ __launch_bounds__(256) void k_gemm1(
        const float* __restrict__ x,
        const u16* __restrict__ whiT, const u16* __restrict__ wloT,
        const float* __restrict__ att_src, const float* __restrict__ att_dst,
        float* __restrict__ h1, float* __restrict__ asrc, float* __restrict__ adst){
    __shared__ u16 Ahi[64*64];   // 8 KB, XOR-swizzled [row][k]
    __shared__ u16 Alo[64*64];   // 8 KB
    const int tid = threadIdx.x;
    const int wid = tid>>6, l = tid&63;
    const int lq = l>>4, lr = l&15;
    const int rowbase = blockIdx.x*64;

    f32x4 acc[4];
    #pragma unroll
    for (int n=0;n<4;n++) acc[n] = (f32x4){0.f,0.f,0.f,0.f};

    for (int ks=0; ks<8; ks++){
        const int k0 = ks*64;
        __syncthreads();
        #pragma unroll
        for (int q=0;q<4;q++){
            int p = tid + 256*q;
            int r = p>>4, kseg = p&15;
            int grow = min(rowbase + r, N_NODES-1);
            float4 v = *(const float4*)(x + (size_t)grow*F_IN + k0 + kseg*4);
            u16 h0=f2bf(v.x), h1v=f2bf(v.y), h2v=f2bf(v.z), h3v=f2bf(v.w);
            u16 e0=f2bf(v.x-bf2f(h0)), e1=f2bf(v.y-bf2f(h1v)),
                e2=f2bf(v.z-bf2f(h2v)), e3=f2bf(v.w-bf2f(h3v));
            int boff = (r*128 + kseg*8) ^ ((r&7)<<4);
            *(ushort4*)((char*)Ahi + boff) = make_ushort4(h0,h1v,h2v,h3v);
            *(ushort4*)((char*)Alo + boff) = make_ushort4(e0,e1,e2,e3);
        }
        __syncthreads();

        const int arow = wid*16 + lr;
        bf16x8 ahi[2], alo[2];
        #pragma unroll
        for (int kt=0;kt<2;kt++){
            int boff = (arow*128 + kt*64 + lq*16) ^ ((arow&7)<<4);
            ahi[kt] = *(const bf16x8*)((const char*)Ahi + boff);
            alo[kt] = *(const bf16x8*)((const char*)Alo + boff);
        }
        #pragma unroll
        for (int n=0;n<4;n++){
            #pragma unroll
            for (int kt=0;kt<2;kt++){
                const size_t wo = (size_t)(n*16+lr)*F_IN + k0 + kt*32 + lq*8;
                bf16x8 bhi = *(const bf16x8*)(whiT + wo);
                bf16x8 blo = *(const bf16x8*)(wloT + wo);
                acc[n] = __builtin_amdgcn_mfma_f32_16x16x32_bf16(ahi[kt], bhi, acc[n], 0,0,0);
                acc[n] = __builtin_amdgcn_mfma_f32_16x16x32_bf16(ahi[kt], blo, acc[n], 0,0,0);
                acc[n] = __builtin_amdgcn_mfma_f32_16x16x32_bf16(alo[kt], bhi, acc[n], 0,0,0);
            }
        }
    }

    // epilogue: C/D layout col=lane&15, row=(lane>>4)*4+i  [HW-verified]
    #pragma unroll
    for (int n=0;n<4;n++){
        int col = n*16 + lr;
        float as_w = att_src[col], ad_w = att_dst[col];
        #pragma unroll
        for (int i=0;i<4;i++){
            int node = rowbase + wid*16 + lq*4 + i;
            float v = acc[n][i];
            float s = v*as_w, d = v*ad_w;
            s += __shfl_xor(s,1); d += __shfl_xor(d,1);
            s += __shfl_xor(s,2); d += __shfl_xor(d,2);
            s += __shfl_xor(s,4); d += __shfl_xor(d,4);
            if (node < N_NODES){
                h1[(size_t)node*D1 + col] = v;
                if ((l&7)==0){
                    int head = col>>3;
                    asrc[node*H1 + head] = s;
                    adst[node*H1 + head] = d;
                }
            }
        }
    }
}

// ---------------------------------------------------------------- layer1 aggregation (weights fused in-loop)
__global__ __launch_bounds__(256) void k_agg1(
        const int* __restrict__ rowptr, const int* __restrict__ srcs,
        const float* __restrict__ asrc1, const float* __restrict__ adst1,
        const float* __restrict__ h1, float* __restrict__ out1){
    const int node = blockIdx.x*4 + (threadIdx.x>>6);
    const int c = threadIdx.x & 63;
    const int h = c >> 3;
    const int r0 = __builtin_amdgcn_readfirstlane(rowptr[node]);
    const int r1 = __builtin_amdgcn_readfirstlane(rowptr[node+1]);
    const float ad = adst1[node*H1 + h];
    float acc = 0.f, den = 0.f;
    #pragma unroll 4
    for (int j=r0; j<r1; j++){
        int s = __builtin_amdgcn_readfirstlane(srcs[j]);
        float w = __expf(leaky(asrc1[s*H1 + h] + ad));   // 32B broadcast + 5 VALU
        acc += w * h1[(size_t)s*D1 + c];
        den += w;
    }
    out1[(size_t)node*D1 + c] = acc/den;
}

// ---------------------------------------------------------------- GEMM2 via MFMA: h2 = elu(out1+b1) @ W2 (+alpha epilogue)
// block 256 thr = 4 waves; tile 64 nodes x 128 cols; K=64 single step
__global__ __launch_bounds__(256) void k_gemm2(
        const float* __restrict__ out1, const float* __restrict__ b1,
        const u16* __restrict__ w2hiT, const u16* __restrict__ w2loT,
        const float* __restrict__ att_src2, const float* __restrict__ att_dst2,
        float* __restrict__ h2, float* __restrict__ asrc2, float* __restrict__ adst2){
    __shared__ u16 Ahi[64*64];   // 8 KB, XOR-swizzled
    __shared__ u16 Alo[64*64];   // 8 KB
    const int tid = threadIdx.x;
    const int wid = tid>>6, l = tid&63;
    const int lq = l>>4, lr = l&15;
    const int rowbase = blockIdx.x*64;

    // stage A = elu(out1 + b1), split hi/lo bf16
    #pragma unroll
    for (int q=0;q<4;q++){
        int p = tid + 256*q;
        int r = p>>4, kseg = p&15;
        int grow = min(rowbase + r, N_NODES-1);
        float4 v = *(const float4*)(out1 + (size_t)grow*D1 + kseg*4);
        float4 bb = *(const float4*)(b1 + kseg*4);
        float a0 = v.x+bb.x, a1 = v.y+bb.y, a2 = v.z+bb.z, a3 = v.w+bb.w;
        a0 = a0>0.f ? a0 : (__expf(a0)-1.f);
        a1 = a1>0.f ? a1 : (__expf(a1)-1.f);
        a2 = a2>0.f ? a2 : (__expf(a2)-1.f);
        a3 = a3>0.f ? a3 : (__expf(a3)-1.f);
        u16 h0=f2bf(a0), h1v=f2bf(a1), h2v=f2bf(a2), h3v=f2bf(a3);
        u16 e0=f2bf(a0-bf2f(h0)), e1=f2bf(a1-bf2f(h1v)),
            e2=f2bf(a2-bf2f(h2v)), e3=f2bf(a3-bf2f(h3v));
        int boff = (r*128 + kseg*8) ^ ((r&7)<<4);
        *(ushort4*)((char*)Ahi + boff) = make_ushort4(h0,h1v,h2v,h3v);
        *(ushort4*)((char*)Alo + boff) = make_ushort4(e0,e1,e2,e3);
    }
    __syncthreads();

    const int arow = wid*16 + lr;
    bf16x8 ahi[2], alo[2];
    #pragma unroll
    for (int kt=0;kt<2;kt++){
        int boff = (arow*128 + kt*64 + lq*16) ^ ((arow&7)<<4);
        ahi[kt] = *(const bf16x8*)((const char*)Ahi + boff);
        alo[kt] = *(const bf16x8*)((const char*)Alo + boff);
    }

    f32x4 acc[8];
    #pragma unroll
    for (int n=0;n<8;n++) acc[n] = (f32x4){0.f,0.f,0.f,0.f};
    #pragma unroll
    for (int n=0;n<8;n++){
        #pragma unroll
        for (int kt=0;kt<2;kt++){
            const size_t wo = (size_t)(n*16+lr)*D1 + kt*32 + lq*8;
            bf16x8 bhi = *(const bf16x8*)(w2hiT + wo);
            bf16x8 blo = *(const bf16x8*)(w2loT + wo);
            acc[n] = __builtin_amdgcn_mfma_f32_16x16x32_bf16(ahi[kt], bhi, acc[n], 0,0,0);
            acc[n] = __builtin_amdgcn_mfma_f32_16x16x32_bf16(ahi[kt], blo, acc[n], 0,0,0);
            acc[n] = __builtin_amdgcn_mfma_f32_16x16x32_bf16(alo[kt], bhi, acc[n], 0,0,0);
        }
    }

    // epilogue: store h2 + alpha projections (reduce over cols)
    float aw[8], dw[8];
    #pragma unroll
    for (int n=0;n<8;n++){ aw[n]=att_src2[n*16+lr]; dw[n]=att_dst2[n*16+lr]; }
    #pragma unroll
    for (int i=0;i<4;i++){
        int node = rowbase + wid*16 + lq*4 + i;
        bool ok = node < N_NODES;
        float s = 0.f, d = 0.f;
        #pragma unroll
        for (int n=0;n<8;n++){
            float v = acc[n][i];
            s = fmaf(v, aw[n], s);
            d = fmaf(v, dw[n], d);
            if (ok) h2[(size_t)node*OUT_C + n*16 + lr] = v;
        }
        s += __shfl_xor(s,1); d += __shfl_xor(d,1);
        s += __shfl_xor(s,2); d += __shfl_xor(d,2);
        s += __shfl_xor(s,4); d += __shfl_xor(d,4);
        s += __shfl_xor(s,8); d += __shfl_xor(d,8);
        if (ok && lr==0){ asrc2[node]=s; adst2[node]=d; }
    }
}

// ---------------------------------------------------------------- layer2 aggregation (weights fused in-loop)
__global__ __launch_bounds__(256) void k_agg2(
        const int* __restrict__ rowptr, const int* __restrict__ srcs,
        const float* __restrict__ asrc2, const float* __restrict__ adst2,
        const float* __restrict__ h2, const float* __restrict__ b2,
        float* __restrict__ out){
    const int node = blockIdx.x*4 + (threadIdx.x>>6);
    const int lane = threadIdx.x & 63;
    const int r0 = __builtin_amdgcn_readfirstlane(rowptr[node]);
    const int r1 = __builtin_amdgcn_readfirstlane(rowptr[node+1]);
    const float ad = adst2[node];
    const float2* __restrict__ h2v = (const float2*)h2;   // row stride 64
    float ax = 0.f, ay = 0.f, den = 0.f;
    #pragma unroll 4
    for (int j=r0; j<r1; j++){
        int s = __builtin_amdgcn_readfirstlane(srcs[j]);
        float w = __expf(leaky(asrc2[s] + ad));   // uniform + 5 VALU
        float2 v = h2v[(size_t)s*64 + lane];
        ax += w*v.x; ay += w*v.y; den += w;
    }
    float inv = 1.f/den;
    float2 bb = ((const float2*)b2)[lane];
    float2 o; o.x = ax*inv + bb.x; o.y = ay*inv + bb.y;
    *(float2*)&out[(size_t)node*OUT_C + lane*2] = o;
}

// ---------------------------------------------------------------- launch
extern "C" void kernel_launch(void* const* d_in, const int* in_sizes, int n_in,
                              void* d_out, int out_size, void* d_ws, size_t ws_size,
                              hipStream_t stream) {
    const float* x        = (const float*)d_in[0];
    const int*   edge     = (const int*)  d_in[1];
    const float* W1       = (const float*)d_in[2];
    const float* att_src1 = (const float*)d_in[3];
    const float* att_dst1 = (const float*)d_in[4];
    const float* b1       = (const float*)d_in[5];
    const float* W2       = (const float*)d_in[6];
    const float* att_src2 = (const float*)d_in[7];
    const float* att_dst2 = (const float*)d_in[8];
    const float* b2       = (const float*)d_in[9];
    float* out = (float*)d_out;

    const int E  = in_sizes[1] / 2;
    const int ET = E + N_NODES;
    const int* src_a = edge;
    const int* dst_a = edge + E;

    // workspace layout
    float* ws = (float*)d_ws;
    float* h1    = ws;                            // N*64
    float* asrc1 = h1    + (size_t)N_NODES*D1;    // N*8
    float* adst1 = asrc1 + (size_t)N_NODES*H1;    // N*8
    float* out1  = adst1 + (size_t)N_NODES*H1;    // N*64
    float* h2    = out1  + (size_t)N_NODES*D1;    // N*128
    float* asrc2 = h2    + (size_t)N_NODES*OUT_C; // N
    float* adst2 = asrc2 + N_NODES;               // N
    int*   cnt    = (int*)(adst2 + N_NODES);      // N   (reused as w2hiT/w2loT after scanC)
    int*   rowptr = cnt    + N_NODES;             // N+4
    int*   cur    = rowptr + (N_NODES+4);         // N   (reused as whiT/wloT after scatter)
    int*   srcs   = cur    + N_NODES;             // ET
    int*   bsum   = srcs   + ET;                  // 256
    int*   boff   = bsum   + 256;                 // 256
    u16*   whiT   = (u16*)cur;                    // 64*512 *2 (128 KB, fits in cur's 200 KB)
    u16*   wloT   = whiT + F_IN*D1;
    u16*   w2hiT  = (u16*)cnt;                    // 128*64 *2 (32 KB, fits in cnt's 200 KB)
    u16*   w2loT  = w2hiT + D1*OUT_C;

    // ---- CSR build (counting sort by dst)
    hipLaunchKernelGGL(k_zero_cnt, dim3((N_NODES+255)/256), dim3(256), 0, stream, cnt);
    hipLaunchKernelGGL(k_hist,  dim3((E+255)/256), dim3(256), 0, stream, dst_a, E, cnt);
    hipLaunchKernelGGL(k_scanA, dim3(SNBLK), dim3(256), 0, stream, cnt, bsum);
    hipLaunchKernelGGL(k_scanB, dim3(1), dim3(256), 0, stream, bsum, boff, rowptr);
    hipLaunchKernelGGL(k_scanC, dim3(SNBLK), dim3(256), 0, stream, cnt, boff, rowptr, cur);
    hipLaunchKernelGGL(k_scatter, dim3((ET+255)/256), dim3(256), 0, stream,
                       src_a, dst_a, E, cur, srcs);

    // ---- weight prep (scratch regions dead after scan/scatter)
    hipLaunchKernelGGL(k_cvtW2, dim3((D1*OUT_C+255)/256), dim3(256), 0, stream,
                       W2, w2hiT, w2loT);
    hipLaunchKernelGGL(k_cvtW, dim3((F_IN*D1+255)/256), dim3(256), 0, stream,
                       W1, whiT, wloT);

    // ---- layer 1
    hipLaunchKernelGGL(k_gemm1, dim3((N_NODES+63)/64), dim3(256), 0, stream,
                       x, whiT, wloT, att_src1, att_dst1, h1, asrc1, adst1);
    hipLaunchKernelGGL(k_agg1, dim3(N_NODES/4), dim3(256), 0, stream,
                       rowptr, srcs, asrc1, adst1, h1, out1);

    // ---- layer 2
    hipLaunchKernelGGL(k_gemm2, dim3((N_NODES+63)/64), dim3(256), 0, stream,
                       out1, b1, w2hiT, w2loT, att_src2, att_dst2, h2, asrc2, adst2);
    hipLaunchKernelGGL(k_agg2, dim3(N_NODES/4), dim3(256), 0, stream,
                       rowptr, srcs, asrc2, adst2, h2, b2, out);
}

// Round 7
// 530.853 us; speedup vs baseline: 1.0193x; 1.0193x over previous
//
#include <hip/hip_runtime.h>
#include <math.h>

#define N_NODES 50000
#define F_IN    512
#define H1      8
#define C1      8
#define D1      64    // H1*C1
#define OUT_C   128
#define NEG     0.2f
#define PAD     32    // ints per node for atomic counters (128B line each)

#define SCHUNK  256
#define SNBLK   ((N_NODES + SCHUNK - 1)/SCHUNK)   // 196

using bf16x8 = __attribute__((ext_vector_type(8))) short;
using f32x4  = __attribute__((ext_vector_type(4))) float;
typedef unsigned short u16;
typedef unsigned int   u32;

__device__ __forceinline__ float leaky(float x){
    return fmaxf(x, 0.f) + NEG * fminf(x, 0.f);
}
__device__ __forceinline__ u16 f2bf(float f){           // RNE
    u32 u = __float_as_uint(f);
    u32 r = u + 0x7FFF + ((u>>16)&1);
    return (u16)(r>>16);
}
__device__ __forceinline__ float bf2f(u16 h){ return __uint_as_float(((u32)h)<<16); }

// ---------------------------------------------------------------- init padded counters (self-loop => start at 1)
__global__ void k_zero_cnt(int* cnt){
    int i = blockIdx.x*blockDim.x + threadIdx.x;
    if (i < N_NODES*PAD) cnt[i] = ((i & (PAD-1))==0) ? 1 : 0;
}

__global__ void k_hist(const int* __restrict__ dst_a, int E, int* cnt){
    int i = blockIdx.x*blockDim.x + threadIdx.x;
    if (i >= E) return;
    atomicAdd(cnt + (size_t)dst_a[i]*PAD, 1);
}

// ---------------------------------------------------------------- 3-phase scan (reads padded cnt)
__global__ __launch_bounds__(256) void k_scanA(const int* __restrict__ cnt, int* bsum){
    __shared__ int sm[256];
    int idx = blockIdx.x*256 + threadIdx.x;
    int v = (idx < N_NODES) ? cnt[(size_t)idx*PAD] : 0;
    sm[threadIdx.x] = v; __syncthreads();
    for (int off=128; off>0; off>>=1){
        if (threadIdx.x < off) sm[threadIdx.x] += sm[threadIdx.x+off];
        __syncthreads();
    }
    if (threadIdx.x==0) bsum[blockIdx.x] = sm[0];
}

__global__ __launch_bounds__(256) void k_scanB(const int* __restrict__ bsum, int* boff, int* rowptr){
    __shared__ int sm[256];
    int t = threadIdx.x;
    int v = (t < SNBLK) ? bsum[t] : 0;
    sm[t]=v; __syncthreads();
    for (int off=1; off<256; off<<=1){
        int u = (t>=off)? sm[t-off] : 0;
        __syncthreads();
        sm[t]+=u; __syncthreads();
    }
    if (t < SNBLK) boff[t] = sm[t] - v;       // exclusive
    if (t==255) rowptr[N_NODES] = sm[255];    // total = E + N
}

__global__ __launch_bounds__(256) void k_scanC(const int* __restrict__ cnt, const int* __restrict__ boff,
                                               int* rowptr, int* cur){
    __shared__ int sm[256];
    int idx = blockIdx.x*256 + threadIdx.x;
    int t = threadIdx.x;
    int v = (idx<N_NODES)? cnt[(size_t)idx*PAD] : 0;
    sm[t]=v; __syncthreads();
    for (int off=1; off<256; off<<=1){
        int u = (t>=off)? sm[t-off] : 0;
        __syncthreads();
        sm[t]+=u; __syncthreads();
    }
    if (idx<N_NODES){
        int ex = boff[blockIdx.x] + sm[t] - v;
        rowptr[idx]=ex; cur[(size_t)idx*PAD]=ex;
    }
}

// ---------------------------------------------------------------- scatter: one 4B store per edge (src only)
__global__ void k_scatter(const int* __restrict__ src_a, const int* __restrict__ dst_a,
                          int E, int* cur, int* srcs){
    int i = blockIdx.x*blockDim.x + threadIdx.x;
    int ET = E + N_NODES;
    if (i >= ET) return;
    int s, d;
    if (i < E){ s = src_a[i]; d = dst_a[i]; }
    else      { s = d = i - E; }
    int pos = atomicAdd(cur + (size_t)d*PAD, 1);
    srcs[pos] = s;
}

// ---------------------------------------------------------------- W1 split/transpose: whiT/wloT [64 col][512 k] bf16
__global__ void k_cvtW(const float* __restrict__ W1, u16* __restrict__ whiT, u16* __restrict__ wloT){
    int i = blockIdx.x*blockDim.x + threadIdx.x;   // 0..32767
    if (i >= F_IN*D1) return;
    int k = i >> 6, col = i & 63;
    float v = W1[i];
    u16 hi = f2bf(v);
    float lo = v - bf2f(hi);
    whiT[col*F_IN + k] = hi;
    wloT[col*F_IN + k] = f2bf(lo);
}

// ---------------------------------------------------------------- W2 split/transpose: [128 col][64 k] bf16
__global__ void k_cvtW2(const float* __restrict__ W2, u16* __restrict__ w2hiT, u16* __restrict__ w2loT){
    int i = blockIdx.x*blockDim.x + threadIdx.x;   // 0..8191
    if (i >= D1*OUT_C) return;
    int k = i >> 7, col = i & 127;
    float v = W2[i];
    u16 hi = f2bf(v);
    float lo = v - bf2f(hi);
    w2hiT[col*D1 + k] = hi;
    w2loT[col*D1 + k] = f2bf(lo);
}

// ---------------------------------------------------------------- GEMM1 via MFMA (split-bf16, f32-accurate)
// block: 256 thr = 4 waves; tile 64 nodes x 64 cols; K step 64
__global__ __launch_bounds__(256) void k_gemm1(
        const float* __restrict__ x,
        const u16* __restrict__ whiT, const u16* __restrict__ wloT,
        const float* __restrict__ att_src, const float* __restrict__ att_dst,
        float* __restrict__ h1, float* __restrict__ asrc, float* __restrict__ adst){
    __shared__ u16 Ahi[64*64];   // 8 KB, XOR-swizzled [row][k]
    __shared__ u16 Alo[64*64];   // 8 KB
    const int tid = threadIdx.x;
    const int wid = tid>>6, l = tid&63;
    const int lq = l>>4, lr = l&15;
    const int rowbase = blockIdx.x*64;

    f32x4 acc[4];
    #pragma unroll
    for (int n=0;n<4;n++) acc[n] = (f32x4){0.f,0.f,0.f,0.f};

    for (int ks=0; ks<8; ks++){
        const int k0 = ks*64;
        __syncthreads();
        #pragma unroll
        for (int q=0;q<4;q++){
            int p = tid + 256*q;
            int r = p>>4, kseg = p&15;
            int grow = min(rowbase + r, N_NODES-1);
            float4 v = *(const float4*)(x + (size_t)grow*F_IN + k0 + kseg*4);
            u16 h0=f2bf(v.x), h1v=f2bf(v.y), h2v=f2bf(v.z), h3v=f2bf(v.w);
            u16 e0=f2bf(v.x-bf2f(h0)), e1=f2bf(v.y-bf2f(h1v)),
                e2=f2bf(v.z-bf2f(h2v)), e3=f2bf(v.w-bf2f(h3v));
            int boff = (r*128 + kseg*8) ^ ((r&7)<<4);
            *(ushort4*)((char*)Ahi + boff) = make_ushort4(h0,h1v,h2v,h3v);
            *(ushort4*)((char*)Alo + boff) = make_ushort4(e0,e1,e2,e3);
        }
        __syncthreads();

        const int arow = wid*16 + lr;
        bf16x8 ahi[2], alo[2];
        #pragma unroll
        for (int kt=0;kt<2;kt++){
            int boff = (arow*128 + kt*64 + lq*16) ^ ((arow&7)<<4);
            ahi[kt] = *(const bf16x8*)((const char*)Ahi + boff);
            alo[kt] = *(const bf16x8*)((const char*)Alo + boff);
        }
        #pragma unroll
        for (int n=0;n<4;n++){
            #pragma unroll
            for (int kt=0;kt<2;kt++){
                const size_t wo = (size_t)(n*16+lr)*F_IN + k0 + kt*32 + lq*8;
                bf16x8 bhi = *(const bf16x8*)(whiT + wo);
                bf16x8 blo = *(const bf16x8*)(wloT + wo);
                acc[n] = __builtin_amdgcn_mfma_f32_16x16x32_bf16(ahi[kt], bhi, acc[n], 0,0,0);
                acc[n] = __builtin_amdgcn_mfma_f32_16x16x32_bf16(ahi[kt], blo, acc[n], 0,0,0);
                acc[n] = __builtin_amdgcn_mfma_f32_16x16x32_bf16(alo[kt], bhi, acc[n], 0,0,0);
            }
        }
    }

    // epilogue: C/D layout col=lane&15, row=(lane>>4)*4+i  [HW-verified]
    #pragma unroll
    for (int n=0;n<4;n++){
        int col = n*16 + lr;
        float as_w = att_src[col], ad_w = att_dst[col];
        #pragma unroll
        for (int i=0;i<4;i++){
            int node = rowbase + wid*16 + lq*4 + i;
            float v = acc[n][i];
            float s = v*as_w, d = v*ad_w;
            s += __shfl_xor(s,1); d += __shfl_xor(d,1);
            s += __shfl_xor(s,2); d += __shfl_xor(d,2);
            s += __shfl_xor(s,4); d += __shfl_xor(d,4);
            if (node < N_NODES){
                h1[(size_t)node*D1 + col] = v;
                if ((l&7)==0){
                    int head = col>>3;
                    asrc[node*H1 + head] = s;
                    adst[node*H1 + head] = d;
                }
            }
        }
    }
}

// ---------------------------------------------------------------- layer1 aggregation (weights fused in-loop)
__global__ __launch_bounds__(256) void k_agg1(
        const int* __restrict__ rowptr, const int* __restrict__ srcs,
        const float* __restrict__ asrc1, const float* __restrict__ adst1,
        const float* __restrict__ h1, float* __restrict__ out1){
    const int node = blockIdx.x*4 + (threadIdx.x>>6);
    const int c = threadIdx.x & 63;
    const int h = c >> 3;
    const int r0 = __builtin_amdgcn_readfirstlane(rowptr[node]);
    const int r1 = __builtin_amdgcn_readfirstlane(rowptr[node+1]);
    const float ad = adst1[node*H1 + h];
    float acc = 0.f, den = 0.f;
    #pragma unroll 4
    for (int j=r0; j<r1; j++){
        int s = __builtin_amdgcn_readfirstlane(srcs[j]);
        float w = __expf(leaky(asrc1[s*H1 + h] + ad));   // 32B broadcast + 5 VALU
        acc += w * h1[(size_t)s*D1 + c];
        den += w;
    }
    out1[(size_t)node*D1 + c] = acc/den;
}

// ---------------------------------------------------------------- GEMM2 via MFMA: h2 = elu(out1+b1) @ W2 (+alpha epilogue)
// block 256 thr = 4 waves; tile 64 nodes x 128 cols; K=64 single step
__global__ __launch_bounds__(256) void k_gemm2(
        const float* __restrict__ out1, const float* __restrict__ b1,
        const u16* __restrict__ w2hiT, const u16* __restrict__ w2loT,
        const float* __restrict__ att_src2, const float* __restrict__ att_dst2,
        float* __restrict__ h2, float* __restrict__ asrc2, float* __restrict__ adst2){
    __shared__ u16 Ahi[64*64];   // 8 KB, XOR-swizzled
    __shared__ u16 Alo[64*64];   // 8 KB
    const int tid = threadIdx.x;
    const int wid = tid>>6, l = tid&63;
    const int lq = l>>4, lr = l&15;
    const int rowbase = blockIdx.x*64;

    // stage A = elu(out1 + b1), split hi/lo bf16
    #pragma unroll
    for (int q=0;q<4;q++){
        int p = tid + 256*q;
        int r = p>>4, kseg = p&15;
        int grow = min(rowbase + r, N_NODES-1);
        float4 v = *(const float4*)(out1 + (size_t)grow*D1 + kseg*4);
        float4 bb = *(const float4*)(b1 + kseg*4);
        float a0 = v.x+bb.x, a1 = v.y+bb.y, a2 = v.z+bb.z, a3 = v.w+bb.w;
        a0 = a0>0.f ? a0 : (__expf(a0)-1.f);
        a1 = a1>0.f ? a1 : (__expf(a1)-1.f);
        a2 = a2>0.f ? a2 : (__expf(a2)-1.f);
        a3 = a3>0.f ? a3 : (__expf(a3)-1.f);
        u16 h0=f2bf(a0), h1v=f2bf(a1), h2v=f2bf(a2), h3v=f2bf(a3);
        u16 e0=f2bf(a0-bf2f(h0)), e1=f2bf(a1-bf2f(h1v)),
            e2=f2bf(a2-bf2f(h2v)), e3=f2bf(a3-bf2f(h3v));
        int boff = (r*128 + kseg*8) ^ ((r&7)<<4);
        *(ushort4*)((char*)Ahi + boff) = make_ushort4(h0,h1v,h2v,h3v);
        *(ushort4*)((char*)Alo + boff) = make_ushort4(e0,e1,e2,e3);
    }
    __syncthreads();

    const int arow = wid*16 + lr;
    bf16x8 ahi[2], alo[2];
    #pragma unroll
    for (int kt=0;kt<2;kt++){
        int boff = (arow*128 + kt*64 + lq*16) ^ ((arow&7)<<4);
        ahi[kt] = *(const bf16x8*)((const char*)Ahi + boff);
        alo[kt] = *(const bf16x8*)((const char*)Alo + boff);
    }

    f32x4 acc[8];
    #pragma unroll
    for (int n=0;n<8;n++) acc[n] = (f32x4){0.f,0.f,0.f,0.f};
    #pragma unroll
    for (int n=0;n<8;n++){
        #pragma unroll
        for (int kt=0;kt<2;kt++){
            const size_t wo = (size_t)(n*16+lr)*D1 + kt*32 + lq*8;
            bf16x8 bhi = *(const bf16x8*)(w2hiT + wo);
            bf16x8 blo = *(const bf16x8*)(w2loT + wo);
            acc[n] = __builtin_amdgcn_mfma_f32_16x16x32_bf16(ahi[kt], bhi, acc[n], 0,0,0);
            acc[n] = __builtin_amdgcn_mfma_f32_16x16x32_bf16(ahi[kt], blo, acc[n], 0,0,0);
            acc[n] = __builtin_amdgcn_mfma_f32_16x16x32_bf16(alo[kt], bhi, acc[n], 0,0,0);
        }
    }

    // epilogue: store h2 + alpha projections (reduce over cols)
    float aw[8], dw[8];
    #pragma unroll
    for (int n=0;n<8;n++){ aw[n]=att_src2[n*16+lr]; dw[n]=att_dst2[n*16+lr]; }
    #pragma unroll
    for (int i=0;i<4;i++){
        int node = rowbase + wid*16 + lq*4 + i;
        bool ok = node < N_NODES;
        float s = 0.f, d = 0.f;
        #pragma unroll
        for (int n=0;n<8;n++){
            float v = acc[n][i];
            s = fmaf(v, aw[n], s);
            d = fmaf(v, dw[n], d);
            if (ok) h2[(size_t)node*OUT_C + n*16 + lr] = v;
        }
        s += __shfl_xor(s,1); d += __shfl_xor(d,1);
        s += __shfl_xor(s,2); d += __shfl_xor(d,2);
        s += __shfl_xor(s,4); d += __shfl_xor(d,4);
        s += __shfl_xor(s,8); d += __shfl_xor(d,8);
        if (ok && lr==0){ asrc2[node]=s; adst2[node]=d; }
    }
}

// ---------------------------------------------------------------- layer2 aggregation (weights fused in-loop)
__global__ __launch_bounds__(256) void k_agg2(
        const int* __restrict__ rowptr, const int* __restrict__ srcs,
        const float* __restrict__ asrc2, const float* __restrict__ adst2,
        const float* __restrict__ h2, const float* __restrict__ b2,
        float* __restrict__ out){
    const int node = blockIdx.x*4 + (threadIdx.x>>6);
    const int lane = threadIdx.x & 63;
    const int r0 = __builtin_amdgcn_readfirstlane(rowptr[node]);
    const int r1 = __builtin_amdgcn_readfirstlane(rowptr[node+1]);
    const float ad = adst2[node];
    const float2* __restrict__ h2v = (const float2*)h2;   // row stride 64
    float ax = 0.f, ay = 0.f, den = 0.f;
    #pragma unroll 4
    for (int j=r0; j<r1; j++){
        int s = __builtin_amdgcn_readfirstlane(srcs[j]);
        float w = __expf(leaky(asrc2[s] + ad));   // uniform + 5 VALU
        float2 v = h2v[(size_t)s*64 + lane];
        ax += w*v.x; ay += w*v.y; den += w;
    }
    float inv = 1.f/den;
    float2 bb = ((const float2*)b2)[lane];
    float2 o; o.x = ax*inv + bb.x; o.y = ay*inv + bb.y;
    *(float2*)&out[(size_t)node*OUT_C + lane*2] = o;
}

// ---------------------------------------------------------------- launch
extern "C" void kernel_launch(void* const* d_in, const int* in_sizes, int n_in,
                              void* d_out, int out_size, void* d_ws, size_t ws_size,
                              hipStream_t stream) {
    const float* x        = (const float*)d_in[0];
    const int*   edge     = (const int*)  d_in[1];
    const float* W1       = (const float*)d_in[2];
    const float* att_src1 = (const float*)d_in[3];
    const float* att_dst1 = (const float*)d_in[4];
    const float* b1       = (const float*)d_in[5];
    const float* W2       = (const float*)d_in[6];
    const float* att_src2 = (const float*)d_in[7];
    const float* att_dst2 = (const float*)d_in[8];
    const float* b2       = (const float*)d_in[9];
    float* out = (float*)d_out;

    const int E  = in_sizes[1] / 2;
    const int ET = E + N_NODES;
    const int* src_a = edge;
    const int* dst_a = edge + E;

    // workspace layout
    float* ws = (float*)d_ws;
    float* h1    = ws;                            // N*64
    float* asrc1 = h1    + (size_t)N_NODES*D1;    // N*8
    float* adst1 = asrc1 + (size_t)N_NODES*H1;    // N*8
    float* out1  = adst1 + (size_t)N_NODES*H1;    // N*64
    float* h2    = out1  + (size_t)N_NODES*D1;    // N*128
    float* asrc2 = h2    + (size_t)N_NODES*OUT_C; // N
    float* adst2 = asrc2 + N_NODES;               // N
    int*   cnt    = (int*)(adst2 + N_NODES);      // N*PAD (reused as w2hiT/w2loT after scanC)
    int*   rowptr = cnt    + (size_t)N_NODES*PAD; // N+4
    int*   cur    = rowptr + (N_NODES+4);         // N*PAD (reused as whiT/wloT after scatter)
    int*   srcs   = cur    + (size_t)N_NODES*PAD; // ET
    int*   bsum   = srcs   + ET;                  // 256
    int*   boff   = bsum   + 256;                 // 256
    u16*   whiT   = (u16*)cur;                    // 64*512 *2 (128 KB)
    u16*   wloT   = whiT + F_IN*D1;
    u16*   w2hiT  = (u16*)cnt;                    // 128*64 *2 (32 KB)
    u16*   w2loT  = w2hiT + D1*OUT_C;

    // ---- CSR build (counting sort by dst, line-padded atomics)
    hipLaunchKernelGGL(k_zero_cnt, dim3((N_NODES*PAD+255)/256), dim3(256), 0, stream, cnt);
    hipLaunchKernelGGL(k_hist,  dim3((E+255)/256), dim3(256), 0, stream, dst_a, E, cnt);
    hipLaunchKernelGGL(k_scanA, dim3(SNBLK), dim3(256), 0, stream, cnt, bsum);
    hipLaunchKernelGGL(k_scanB, dim3(1), dim3(256), 0, stream, bsum, boff, rowptr);
    hipLaunchKernelGGL(k_scanC, dim3(SNBLK), dim3(256), 0, stream, cnt, boff, rowptr, cur);
    hipLaunchKernelGGL(k_scatter, dim3((ET+255)/256), dim3(256), 0, stream,
                       src_a, dst_a, E, cur, srcs);

    // ---- weight prep (scratch regions dead after scan/scatter)
    hipLaunchKernelGGL(k_cvtW2, dim3((D1*OUT_C+255)/256), dim3(256), 0, stream,
                       W2, w2hiT, w2loT);
    hipLaunchKernelGGL(k_cvtW, dim3((F_IN*D1+255)/256), dim3(256), 0, stream,
                       W1, whiT, wloT);

    // ---- layer 1
    hipLaunchKernelGGL(k_gemm1, dim3((N_NODES+63)/64), dim3(256), 0, stream,
                       x, whiT, wloT, att_src1, att_dst1, h1, asrc1, adst1);
    hipLaunchKernelGGL(k_agg1, dim3(N_NODES/4), dim3(256), 0, stream,
                       rowptr, srcs, asrc1, adst1, h1, out1);

    // ---- layer 2
    hipLaunchKernelGGL(k_gemm2, dim3((N_NODES+63)/64), dim3(256), 0, stream,
                       out1, b1, w2hiT, w2loT, att_src2, att_dst2, h2, asrc2, adst2);
    hipLaunchKernelGGL(k_agg2, dim3(N_NODES/4), dim3(256), 0, stream,
                       rowptr, srcs, asrc2, adst2, h2, b2, out);
}

// Round 8
// 418.409 us; speedup vs baseline: 1.2932x; 1.2687x over previous
//
#include <hip/hip_runtime.h>
#include <math.h>

#define N_NODES 50000
#define F_IN    512
#define H1      8
#define C1      8
#define D1      64    // H1*C1
#define OUT_C   128
#define NEG     0.2f

#define SCHUNK  256
#define SNBLK   ((N_NODES + SCHUNK - 1)/SCHUNK)   // 196

#define NHB      256    // histogram/scatter blocks
#define HTHREADS 1024
#define HALF     25000  // nodes per LDS pass
#define HWORDS   12500  // packed u32 words per pass (2 u16 counters each)

using bf16x8 = __attribute__((ext_vector_type(8))) short;
using f32x4  = __attribute__((ext_vector_type(4))) float;
typedef unsigned short u16;
typedef unsigned int   u32;

__device__ __forceinline__ float leaky(float x){
    return fmaxf(x, 0.f) + NEG * fminf(x, 0.f);
}
__device__ __forceinline__ u16 f2bf(float f){           // RNE
    u32 u = __float_as_uint(f);
    u32 r = u + 0x7FFF + ((u>>16)&1);
    return (u16)(r>>16);
}
__device__ __forceinline__ float bf2f(u16 h){ return __uint_as_float(((u32)h)<<16); }

// ---------------------------------------------------------------- per-block LDS histogram -> histmat[blk][node]
__global__ __launch_bounds__(1024) void k_histB(const int* __restrict__ dst_a, int E, int CE,
                                                u32* __restrict__ histmat){
    __shared__ u32 lcnt[HWORDS];
    const int blk = blockIdx.x;
    const int i0 = blk*CE;
    const int i1 = min(i0+CE, E + N_NODES);
    for (int p=0;p<2;p++){
        for (int w=threadIdx.x; w<HWORDS; w+=HTHREADS) lcnt[w]=0;
        __syncthreads();
        const int lo = p*HALF, hi = lo+HALF;
        for (int i=i0+(int)threadIdx.x; i<i1; i+=HTHREADS){
            int d = (i<E)? dst_a[i] : (i-E);
            if (d>=lo && d<hi){
                int dd = d - lo;
                atomicAdd(&lcnt[dd>>1], 1u<<((dd&1)*16));
            }
        }
        __syncthreads();
        uint2* dst = (uint2*)(histmat + (size_t)blk*N_NODES + lo);
        for (int w=threadIdx.x; w<HWORDS; w+=HTHREADS){
            u32 v = lcnt[w];
            dst[w] = make_uint2(v & 0xFFFFu, v >> 16);
        }
        __syncthreads();
    }
}

// ---------------------------------------------------------------- column scan: histmat -> per-block exclusive prefix, cnt
__global__ __launch_bounds__(256) void k_colscan(u32* __restrict__ histmat, int* __restrict__ cnt){
    int n = blockIdx.x*256 + threadIdx.x;
    if (n >= N_NODES) return;
    u32 run = 0;
    u32* p = histmat + n;
    #pragma unroll 4
    for (int b=0;b<NHB;b++){
        u32 v = p[(size_t)b*N_NODES];
        p[(size_t)b*N_NODES] = run;
        run += v;
    }
    cnt[n] = (int)run;
}

// ---------------------------------------------------------------- 3-phase scan over cnt -> rowptr
__global__ __launch_bounds__(256) void k_scanA(const int* __restrict__ cnt, int* bsum){
    __shared__ int sm[256];
    int idx = blockIdx.x*256 + threadIdx.x;
    int v = (idx < N_NODES) ? cnt[idx] : 0;
    sm[threadIdx.x] = v; __syncthreads();
    for (int off=128; off>0; off>>=1){
        if (threadIdx.x < off) sm[threadIdx.x] += sm[threadIdx.x+off];
        __syncthreads();
    }
    if (threadIdx.x==0) bsum[blockIdx.x] = sm[0];
}

__global__ __launch_bounds__(256) void k_scanB(const int* __restrict__ bsum, int* boff, int* rowptr){
    __shared__ int sm[256];
    int t = threadIdx.x;
    int v = (t < SNBLK) ? bsum[t] : 0;
    sm[t]=v; __syncthreads();
    for (int off=1; off<256; off<<=1){
        int u = (t>=off)? sm[t-off] : 0;
        __syncthreads();
        sm[t]+=u; __syncthreads();
    }
    if (t < SNBLK) boff[t] = sm[t] - v;       // exclusive
    if (t==255) rowptr[N_NODES] = sm[255];    // total = E + N
}

__global__ __launch_bounds__(256) void k_scanC(const int* __restrict__ cnt, const int* __restrict__ boff,
                                               int* rowptr){
    __shared__ int sm[256];
    int idx = blockIdx.x*256 + threadIdx.x;
    int t = threadIdx.x;
    int v = (idx<N_NODES)? cnt[idx] : 0;
    sm[t]=v; __syncthreads();
    for (int off=1; off<256; off<<=1){
        int u = (t>=off)? sm[t-off] : 0;
        __syncthreads();
        sm[t]+=u; __syncthreads();
    }
    if (idx<N_NODES){
        rowptr[idx] = boff[blockIdx.x] + sm[t] - v;
    }
}

// ---------------------------------------------------------------- atomic-free scatter (LDS local ranks)
__global__ __launch_bounds__(1024) void k_scatterB(const int* __restrict__ src_a, const int* __restrict__ dst_a,
                                                   int E, int CE,
                                                   const u32* __restrict__ histmat, const int* __restrict__ rowptr,
                                                   int* __restrict__ srcs){
    __shared__ u32 lcnt[HWORDS];
    const int blk = blockIdx.x;
    const int i0 = blk*CE;
    const int i1 = min(i0+CE, E + N_NODES);
    const u32* __restrict__ pb = histmat + (size_t)blk*N_NODES;
    for (int p=0;p<2;p++){
        for (int w=threadIdx.x; w<HWORDS; w+=HTHREADS) lcnt[w]=0;
        __syncthreads();
        const int lo = p*HALF, hi = lo+HALF;
        for (int i=i0+(int)threadIdx.x; i<i1; i+=HTHREADS){
            int s, d;
            if (i<E){ s=src_a[i]; d=dst_a[i]; } else { s=d=i-E; }
            if (d>=lo && d<hi){
                int dd = d - lo;
                u32 old = atomicAdd(&lcnt[dd>>1], 1u<<((dd&1)*16));
                u32 rank = (old >> ((dd&1)*16)) & 0xFFFFu;
                int pos = rowptr[d] + (int)pb[d] + (int)rank;
                srcs[pos] = s;
            }
        }
        __syncthreads();
    }
}

// ---------------------------------------------------------------- W1 split/transpose: whiT/wloT [64 col][512 k] bf16
__global__ void k_cvtW(const float* __restrict__ W1, u16* __restrict__ whiT, u16* __restrict__ wloT){
    int i = blockIdx.x*blockDim.x + threadIdx.x;   // 0..32767
    if (i >= F_IN*D1) return;
    int k = i >> 6, col = i & 63;
    float v = W1[i];
    u16 hi = f2bf(v);
    float lo = v - bf2f(hi);
    whiT[col*F_IN + k] = hi;
    wloT[col*F_IN + k] = f2bf(lo);
}

// ---------------------------------------------------------------- W2 split/transpose: [128 col][64 k] bf16
__global__ void k_cvtW2(const float* __restrict__ W2, u16* __restrict__ w2hiT, u16* __restrict__ w2loT){
    int i = blockIdx.x*blockDim.x + threadIdx.x;   // 0..8191
    if (i >= D1*OUT_C) return;
    int k = i >> 7, col = i & 127;
    float v = W2[i];
    u16 hi = f2bf(v);
    float lo = v - bf2f(hi);
    w2hiT[col*D1 + k] = hi;
    w2loT[col*D1 + k] = f2bf(lo);
}

// ---------------------------------------------------------------- GEMM1 via MFMA (split-bf16, f32-accurate)
__global__ __launch_bounds__(256) void k_gemm1(
        const float* __restrict__ x,
        const u16* __restrict__ whiT, const u16* __restrict__ wloT,
        const float* __restrict__ att_src, const float* __restrict__ att_dst,
        float* __restrict__ h1, float* __restrict__ asrc, float* __restrict__ adst){
    __shared__ u16 Ahi[64*64];   // 8 KB, XOR-swizzled [row][k]
    __shared__ u16 Alo[64*64];   // 8 KB
    const int tid = threadIdx.x;
    const int wid = tid>>6, l = tid&63;
    const int lq = l>>4, lr = l&15;
    const int rowbase = blockIdx.x*64;

    f32x4 acc[4];
    #pragma unroll
    for (int n=0;n<4;n++) acc[n] = (f32x4){0.f,0.f,0.f,0.f};

    for (int ks=0; ks<8; ks++){
        const int k0 = ks*64;
        __syncthreads();
        #pragma unroll
        for (int q=0;q<4;q++){
            int p = tid + 256*q;
            int r = p>>4, kseg = p&15;
            int grow = min(rowbase + r, N_NODES-1);
            float4 v = *(const float4*)(x + (size_t)grow*F_IN + k0 + kseg*4);
            u16 h0=f2bf(v.x), h1v=f2bf(v.y), h2v=f2bf(v.z), h3v=f2bf(v.w);
            u16 e0=f2bf(v.x-bf2f(h0)), e1=f2bf(v.y-bf2f(h1v)),
                e2=f2bf(v.z-bf2f(h2v)), e3=f2bf(v.w-bf2f(h3v));
            int boff = (r*128 + kseg*8) ^ ((r&7)<<4);
            *(ushort4*)((char*)Ahi + boff) = make_ushort4(h0,h1v,h2v,h3v);
            *(ushort4*)((char*)Alo + boff) = make_ushort4(e0,e1,e2,e3);
        }
        __syncthreads();

        const int arow = wid*16 + lr;
        bf16x8 ahi[2], alo[2];
        #pragma unroll
        for (int kt=0;kt<2;kt++){
            int boff = (arow*128 + kt*64 + lq*16) ^ ((arow&7)<<4);
            ahi[kt] = *(const bf16x8*)((const char*)Ahi + boff);
            alo[kt] = *(const bf16x8*)((const char*)Alo + boff);
        }
        #pragma unroll
        for (int n=0;n<4;n++){
            #pragma unroll
            for (int kt=0;kt<2;kt++){
                const size_t wo = (size_t)(n*16+lr)*F_IN + k0 + kt*32 + lq*8;
                bf16x8 bhi = *(const bf16x8*)(whiT + wo);
                bf16x8 blo = *(const bf16x8*)(wloT + wo);
                acc[n] = __builtin_amdgcn_mfma_f32_16x16x32_bf16(ahi[kt], bhi, acc[n], 0,0,0);
                acc[n] = __builtin_amdgcn_mfma_f32_16x16x32_bf16(ahi[kt], blo, acc[n], 0,0,0);
                acc[n] = __builtin_amdgcn_mfma_f32_16x16x32_bf16(alo[kt], bhi, acc[n], 0,0,0);
            }
        }
    }

    // epilogue: C/D layout col=lane&15, row=(lane>>4)*4+i  [HW-verified]
    #pragma unroll
    for (int n=0;n<4;n++){
        int col = n*16 + lr;
        float as_w = att_src[col], ad_w = att_dst[col];
        #pragma unroll
        for (int i=0;i<4;i++){
            int node = rowbase + wid*16 + lq*4 + i;
            float v = acc[n][i];
            float s = v*as_w, d = v*ad_w;
            s += __shfl_xor(s,1); d += __shfl_xor(d,1);
            s += __shfl_xor(s,2); d += __shfl_xor(d,2);
            s += __shfl_xor(s,4); d += __shfl_xor(d,4);
            if (node < N_NODES){
                h1[(size_t)node*D1 + col] = v;
                if ((l&7)==0){
                    int head = col>>3;
                    asrc[node*H1 + head] = s;
                    adst[node*H1 + head] = d;
                }
            }
        }
    }
}

// ---------------------------------------------------------------- layer1 aggregation (weights fused in-loop)
__global__ __launch_bounds__(256) void k_agg1(
        const int* __restrict__ rowptr, const int* __restrict__ srcs,
        const float* __restrict__ asrc1, const float* __restrict__ adst1,
        const float* __restrict__ h1, float* __restrict__ out1){
    const int node = blockIdx.x*4 + (threadIdx.x>>6);
    const int c = threadIdx.x & 63;
    const int h = c >> 3;
    const int r0 = __builtin_amdgcn_readfirstlane(rowptr[node]);
    const int r1 = __builtin_amdgcn_readfirstlane(rowptr[node+1]);
    const float ad = adst1[node*H1 + h];
    float acc = 0.f, den = 0.f;
    #pragma unroll 4
    for (int j=r0; j<r1; j++){
        int s = __builtin_amdgcn_readfirstlane(srcs[j]);
        float w = __expf(leaky(asrc1[s*H1 + h] + ad));
        acc += w * h1[(size_t)s*D1 + c];
        den += w;
    }
    out1[(size_t)node*D1 + c] = acc/den;
}

// ---------------------------------------------------------------- GEMM2 via MFMA: h2 = elu(out1+b1) @ W2 (+alpha epilogue)
__global__ __launch_bounds__(256) void k_gemm2(
        const float* __restrict__ out1, const float* __restrict__ b1,
        const u16* __restrict__ w2hiT, const u16* __restrict__ w2loT,
        const float* __restrict__ att_src2, const float* __restrict__ att_dst2,
        float* __restrict__ h2, float* __restrict__ asrc2, float* __restrict__ adst2){
    __shared__ u16 Ahi[64*64];   // 8 KB, XOR-swizzled
    __shared__ u16 Alo[64*64];   // 8 KB
    const int tid = threadIdx.x;
    const int wid = tid>>6, l = tid&63;
    const int lq = l>>4, lr = l&15;
    const int rowbase = blockIdx.x*64;

    #pragma unroll
    for (int q=0;q<4;q++){
        int p = tid + 256*q;
        int r = p>>4, kseg = p&15;
        int grow = min(rowbase + r, N_NODES-1);
        float4 v = *(const float4*)(out1 + (size_t)grow*D1 + kseg*4);
        float4 bb = *(const float4*)(b1 + kseg*4);
        float a0 = v.x+bb.x, a1 = v.y+bb.y, a2 = v.z+bb.z, a3 = v.w+bb.w;
        a0 = a0>0.f ? a0 : (__expf(a0)-1.f);
        a1 = a1>0.f ? a1 : (__expf(a1)-1.f);
        a2 = a2>0.f ? a2 : (__expf(a2)-1.f);
        a3 = a3>0.f ? a3 : (__expf(a3)-1.f);
        u16 h0=f2bf(a0), h1v=f2bf(a1), h2v=f2bf(a2), h3v=f2bf(a3);
        u16 e0=f2bf(a0-bf2f(h0)), e1=f2bf(a1-bf2f(h1v)),
            e2=f2bf(a2-bf2f(h2v)), e3=f2bf(a3-bf2f(h3v));
        int boff = (r*128 + kseg*8) ^ ((r&7)<<4);
        *(ushort4*)((char*)Ahi + boff) = make_ushort4(h0,h1v,h2v,h3v);
        *(ushort4*)((char*)Alo + boff) = make_ushort4(e0,e1,e2,e3);
    }
    __syncthreads();

    const int arow = wid*16 + lr;
    bf16x8 ahi[2], alo[2];
    #pragma unroll
    for (int kt=0;kt<2;kt++){
        int boff = (arow*128 + kt*64 + lq*16) ^ ((arow&7)<<4);
        ahi[kt] = *(const bf16x8*)((const char*)Ahi + boff);
        alo[kt] = *(const bf16x8*)((const char*)Alo + boff);
    }

    f32x4 acc[8];
    #pragma unroll
    for (int n=0;n<8;n++) acc[n] = (f32x4){0.f,0.f,0.f,0.f};
    #pragma unroll
    for (int n=0;n<8;n++){
        #pragma unroll
        for (int kt=0;kt<2;kt++){
            const size_t wo = (size_t)(n*16+lr)*D1 + kt*32 + lq*8;
            bf16x8 bhi = *(const bf16x8*)(w2hiT + wo);
            bf16x8 blo = *(const bf16x8*)(w2loT + wo);
            acc[n] = __builtin_amdgcn_mfma_f32_16x16x32_bf16(ahi[kt], bhi, acc[n], 0,0,0);
            acc[n] = __builtin_amdgcn_mfma_f32_16x16x32_bf16(ahi[kt], blo, acc[n], 0,0,0);
            acc[n] = __builtin_amdgcn_mfma_f32_16x16x32_bf16(alo[kt], bhi, acc[n], 0,0,0);
        }
    }

    float aw[8], dw[8];
    #pragma unroll
    for (int n=0;n<8;n++){ aw[n]=att_src2[n*16+lr]; dw[n]=att_dst2[n*16+lr]; }
    #pragma unroll
    for (int i=0;i<4;i++){
        int node = rowbase + wid*16 + lq*4 + i;
        bool ok = node < N_NODES;
        float s = 0.f, d = 0.f;
        #pragma unroll
        for (int n=0;n<8;n++){
            float v = acc[n][i];
            s = fmaf(v, aw[n], s);
            d = fmaf(v, dw[n], d);
            if (ok) h2[(size_t)node*OUT_C + n*16 + lr] = v;
        }
        s += __shfl_xor(s,1); d += __shfl_xor(d,1);
        s += __shfl_xor(s,2); d += __shfl_xor(d,2);
        s += __shfl_xor(s,4); d += __shfl_xor(d,4);
        s += __shfl_xor(s,8); d += __shfl_xor(d,8);
        if (ok && lr==0){ asrc2[node]=s; adst2[node]=d; }
    }
}

// ---------------------------------------------------------------- layer2 aggregation (weights fused in-loop)
__global__ __launch_bounds__(256) void k_agg2(
        const int* __restrict__ rowptr, const int* __restrict__ srcs,
        const float* __restrict__ asrc2, const float* __restrict__ adst2,
        const float* __restrict__ h2, const float* __restrict__ b2,
        float* __restrict__ out){
    const int node = blockIdx.x*4 + (threadIdx.x>>6);
    const int lane = threadIdx.x & 63;
    const int r0 = __builtin_amdgcn_readfirstlane(rowptr[node]);
    const int r1 = __builtin_amdgcn_readfirstlane(rowptr[node+1]);
    const float ad = adst2[node];
    const float2* __restrict__ h2v = (const float2*)h2;   // row stride 64
    float ax = 0.f, ay = 0.f, den = 0.f;
    #pragma unroll 4
    for (int j=r0; j<r1; j++){
        int s = __builtin_amdgcn_readfirstlane(srcs[j]);
        float w = __expf(leaky(asrc2[s] + ad));
        float2 v = h2v[(size_t)s*64 + lane];
        ax += w*v.x; ay += w*v.y; den += w;
    }
    float inv = 1.f/den;
    float2 bb = ((const float2*)b2)[lane];
    float2 o; o.x = ax*inv + bb.x; o.y = ay*inv + bb.y;
    *(float2*)&out[(size_t)node*OUT_C + lane*2] = o;
}

// ---------------------------------------------------------------- launch
extern "C" void kernel_launch(void* const* d_in, const int* in_sizes, int n_in,
                              void* d_out, int out_size, void* d_ws, size_t ws_size,
                              hipStream_t stream) {
    const float* x        = (const float*)d_in[0];
    const int*   edge     = (const int*)  d_in[1];
    const float* W1       = (const float*)d_in[2];
    const float* att_src1 = (const float*)d_in[3];
    const float* att_dst1 = (const float*)d_in[4];
    const float* b1       = (const float*)d_in[5];
    const float* W2       = (const float*)d_in[6];
    const float* att_src2 = (const float*)d_in[7];
    const float* att_dst2 = (const float*)d_in[8];
    const float* b2       = (const float*)d_in[9];
    float* out = (float*)d_out;

    const int E  = in_sizes[1] / 2;
    const int ET = E + N_NODES;
    const int CE = (ET + NHB - 1) / NHB;
    const int* src_a = edge;
    const int* dst_a = edge + E;

    // workspace layout
    float* ws = (float*)d_ws;
    float* h1    = ws;                            // N*64
    float* asrc1 = h1    + (size_t)N_NODES*D1;    // N*8
    float* adst1 = asrc1 + (size_t)N_NODES*H1;    // N*8
    float* out1  = adst1 + (size_t)N_NODES*H1;    // N*64
    float* h2    = out1  + (size_t)N_NODES*D1;    // N*128
    float* asrc2 = h2    + (size_t)N_NODES*OUT_C; // N
    float* adst2 = asrc2 + N_NODES;               // N
    int*   cnt    = (int*)(adst2 + N_NODES);      // N
    int*   rowptr = cnt    + N_NODES;             // N+4
    int*   srcs   = rowptr + (N_NODES+4);         // ET
    int*   bsum   = srcs   + ET;                  // 256
    int*   boff   = bsum   + 256;                 // 256
    u32*   histmat= (u32*)(boff + 256);           // NHB*N (51.2 MB; dead after scatterB)
    u16*   whiT   = (u16*)histmat;                // 64*512 *2 (overlays histmat)
    u16*   wloT   = whiT + F_IN*D1;
    u16*   w2hiT  = wloT + F_IN*D1;               // 128*64 *2
    u16*   w2loT  = w2hiT + D1*OUT_C;

    // ---- CSR build (atomic-free counting sort)
    hipLaunchKernelGGL(k_histB,   dim3(NHB), dim3(HTHREADS), 0, stream, dst_a, E, CE, histmat);
    hipLaunchKernelGGL(k_colscan, dim3(SNBLK), dim3(256), 0, stream, histmat, cnt);
    hipLaunchKernelGGL(k_scanA,   dim3(SNBLK), dim3(256), 0, stream, cnt, bsum);
    hipLaunchKernelGGL(k_scanB,   dim3(1), dim3(256), 0, stream, bsum, boff, rowptr);
    hipLaunchKernelGGL(k_scanC,   dim3(SNBLK), dim3(256), 0, stream, cnt, boff, rowptr);
    hipLaunchKernelGGL(k_scatterB,dim3(NHB), dim3(HTHREADS), 0, stream,
                       src_a, dst_a, E, CE, histmat, rowptr, srcs);

    // ---- weight prep (histmat dead after scatterB)
    hipLaunchKernelGGL(k_cvtW2, dim3((D1*OUT_C+255)/256), dim3(256), 0, stream,
                       W2, w2hiT, w2loT);
    hipLaunchKernelGGL(k_cvtW, dim3((F_IN*D1+255)/256), dim3(256), 0, stream,
                       W1, whiT, wloT);

    // ---- layer 1
    hipLaunchKernelGGL(k_gemm1, dim3((N_NODES+63)/64), dim3(256), 0, stream,
                       x, whiT, wloT, att_src1, att_dst1, h1, asrc1, adst1);
    hipLaunchKernelGGL(k_agg1, dim3(N_NODES/4), dim3(256), 0, stream,
                       rowptr, srcs, asrc1, adst1, h1, out1);

    // ---- layer 2
    hipLaunchKernelGGL(k_gemm2, dim3((N_NODES+63)/64), dim3(256), 0, stream,
                       out1, b1, w2hiT, w2loT, att_src2, att_dst2, h2, asrc2, adst2);
    hipLaunchKernelGGL(k_agg2, dim3(N_NODES/4), dim3(256), 0, stream,
                       rowptr, srcs, asrc2, adst2, h2, b2, out);
}

// Round 9
// 379.003 us; speedup vs baseline: 1.4276x; 1.1040x over previous
//
#include <hip/hip_runtime.h>
#include <math.h>

#define N_NODES 50000
#define F_IN    512
#define H1      8
#define C1      8
#define D1      64    // H1*C1
#define OUT_C   128
#define NEG     0.2f

#define SCHUNK  256
#define SNBLK   ((N_NODES + SCHUNK - 1)/SCHUNK)   // 196

#define NHB      256    // histogram/scatter blocks
#define HTHREADS 1024
#define HALF     25000  // nodes per LDS pass
#define HWORDS   12500  // packed u32 words per pass (2 u16 counters each)

using bf16x8 = __attribute__((ext_vector_type(8))) short;
using f32x4  = __attribute__((ext_vector_type(4))) float;
typedef unsigned short u16;
typedef unsigned int   u32;

__device__ __forceinline__ float leaky(float x){
    return fmaxf(x, 0.f) + NEG * fminf(x, 0.f);
}
__device__ __forceinline__ u16 f2bf(float f){           // RNE
    u32 u = __float_as_uint(f);
    u32 r = u + 0x7FFF + ((u>>16)&1);
    return (u16)(r>>16);
}
__device__ __forceinline__ float bf2f(u16 h){ return __uint_as_float(((u32)h)<<16); }

// ---------------------------------------------------------------- per-block LDS histogram -> histmat[blk][node]
__global__ __launch_bounds__(1024) void k_histB(const int* __restrict__ dst_a, int E, int CE,
                                                u32* __restrict__ histmat){
    __shared__ u32 lcnt[HWORDS];
    const int blk = blockIdx.x;
    const int i0 = blk*CE;
    const int i1 = min(i0+CE, E + N_NODES);
    for (int p=0;p<2;p++){
        for (int w=threadIdx.x; w<HWORDS; w+=HTHREADS) lcnt[w]=0;
        __syncthreads();
        const int lo = p*HALF, hi = lo+HALF;
        for (int i=i0+(int)threadIdx.x; i<i1; i+=HTHREADS){
            int d = (i<E)? dst_a[i] : (i-E);
            if (d>=lo && d<hi){
                int dd = d - lo;
                atomicAdd(&lcnt[dd>>1], 1u<<((dd&1)*16));
            }
        }
        __syncthreads();
        uint2* dst = (uint2*)(histmat + (size_t)blk*N_NODES + lo);
        for (int w=threadIdx.x; w<HWORDS; w+=HTHREADS){
            u32 v = lcnt[w];
            dst[w] = make_uint2(v & 0xFFFFu, v >> 16);
        }
        __syncthreads();
    }
}

// ---------------------------------------------------------------- column scan: histmat -> per-block exclusive prefix, cnt
__global__ __launch_bounds__(256) void k_colscan(u32* __restrict__ histmat, int* __restrict__ cnt){
    int n = blockIdx.x*256 + threadIdx.x;
    if (n >= N_NODES) return;
    u32 run = 0;
    u32* p = histmat + n;
    #pragma unroll 4
    for (int b=0;b<NHB;b++){
        u32 v = p[(size_t)b*N_NODES];
        p[(size_t)b*N_NODES] = run;
        run += v;
    }
    cnt[n] = (int)run;
}

// ---------------------------------------------------------------- 3-phase scan over cnt -> rowptr
__global__ __launch_bounds__(256) void k_scanA(const int* __restrict__ cnt, int* bsum){
    __shared__ int sm[256];
    int idx = blockIdx.x*256 + threadIdx.x;
    int v = (idx < N_NODES) ? cnt[idx] : 0;
    sm[threadIdx.x] = v; __syncthreads();
    for (int off=128; off>0; off>>=1){
        if (threadIdx.x < off) sm[threadIdx.x] += sm[threadIdx.x+off];
        __syncthreads();
    }
    if (threadIdx.x==0) bsum[blockIdx.x] = sm[0];
}

__global__ __launch_bounds__(256) void k_scanB(const int* __restrict__ bsum, int* boff, int* rowptr){
    __shared__ int sm[256];
    int t = threadIdx.x;
    int v = (t < SNBLK) ? bsum[t] : 0;
    sm[t]=v; __syncthreads();
    for (int off=1; off<256; off<<=1){
        int u = (t>=off)? sm[t-off] : 0;
        __syncthreads();
        sm[t]+=u; __syncthreads();
    }
    if (t < SNBLK) boff[t] = sm[t] - v;       // exclusive
    if (t==255) rowptr[N_NODES] = sm[255];    // total = E + N
}

__global__ __launch_bounds__(256) void k_scanC(const int* __restrict__ cnt, const int* __restrict__ boff,
                                               int* rowptr){
    __shared__ int sm[256];
    int idx = blockIdx.x*256 + threadIdx.x;
    int t = threadIdx.x;
    int v = (idx<N_NODES)? cnt[idx] : 0;
    sm[t]=v; __syncthreads();
    for (int off=1; off<256; off<<=1){
        int u = (t>=off)? sm[t-off] : 0;
        __syncthreads();
        sm[t]+=u; __syncthreads();
    }
    if (idx<N_NODES){
        rowptr[idx] = boff[blockIdx.x] + sm[t] - v;
    }
}

// ---------------------------------------------------------------- atomic-free scatter (LDS local ranks)
__global__ __launch_bounds__(1024) void k_scatterB(const int* __restrict__ src_a, const int* __restrict__ dst_a,
                                                   int E, int CE,
                                                   const u32* __restrict__ histmat, const int* __restrict__ rowptr,
                                                   int* __restrict__ srcs){
    __shared__ u32 lcnt[HWORDS];
    const int blk = blockIdx.x;
    const int i0 = blk*CE;
    const int i1 = min(i0+CE, E + N_NODES);
    const u32* __restrict__ pb = histmat + (size_t)blk*N_NODES;
    for (int p=0;p<2;p++){
        for (int w=threadIdx.x; w<HWORDS; w+=HTHREADS) lcnt[w]=0;
        __syncthreads();
        const int lo = p*HALF, hi = lo+HALF;
        for (int i=i0+(int)threadIdx.x; i<i1; i+=HTHREADS){
            int s, d;
            if (i<E){ s=src_a[i]; d=dst_a[i]; } else { s=d=i-E; }
            if (d>=lo && d<hi){
                int dd = d - lo;
                u32 old = atomicAdd(&lcnt[dd>>1], 1u<<((dd&1)*16));
                u32 rank = (old >> ((dd&1)*16)) & 0xFFFFu;
                int pos = rowptr[d] + (int)pb[d] + (int)rank;
                srcs[pos] = s;
            }
        }
        __syncthreads();
    }
}

// ---------------------------------------------------------------- W1 split/transpose: whiT/wloT [64 col][512 k] bf16
__global__ void k_cvtW(const float* __restrict__ W1, u16* __restrict__ whiT, u16* __restrict__ wloT){
    int i = blockIdx.x*blockDim.x + threadIdx.x;   // 0..32767
    if (i >= F_IN*D1) return;
    int k = i >> 6, col = i & 63;
    float v = W1[i];
    u16 hi = f2bf(v);
    float lo = v - bf2f(hi);
    whiT[col*F_IN + k] = hi;
    wloT[col*F_IN + k] = f2bf(lo);
}

// ---------------------------------------------------------------- W2 split/transpose: [128 col][64 k] bf16
__global__ void k_cvtW2(const float* __restrict__ W2, u16* __restrict__ w2hiT, u16* __restrict__ w2loT){
    int i = blockIdx.x*blockDim.x + threadIdx.x;   // 0..8191
    if (i >= D1*OUT_C) return;
    int k = i >> 7, col = i & 127;
    float v = W2[i];
    u16 hi = f2bf(v);
    float lo = v - bf2f(hi);
    w2hiT[col*D1 + k] = hi;
    w2loT[col*D1 + k] = f2bf(lo);
}

// ---------------------------------------------------------------- GEMM1 via MFMA (split-bf16, f32-accurate); h1 stored bf16
__global__ __launch_bounds__(256) void k_gemm1(
        const float* __restrict__ x,
        const u16* __restrict__ whiT, const u16* __restrict__ wloT,
        const float* __restrict__ att_src, const float* __restrict__ att_dst,
        u16* __restrict__ h1b, float* __restrict__ asrc, float* __restrict__ adst){
    __shared__ u16 Ahi[64*64];   // 8 KB, XOR-swizzled [row][k]
    __shared__ u16 Alo[64*64];   // 8 KB
    const int tid = threadIdx.x;
    const int wid = tid>>6, l = tid&63;
    const int lq = l>>4, lr = l&15;
    const int rowbase = blockIdx.x*64;

    f32x4 acc[4];
    #pragma unroll
    for (int n=0;n<4;n++) acc[n] = (f32x4){0.f,0.f,0.f,0.f};

    for (int ks=0; ks<8; ks++){
        const int k0 = ks*64;
        __syncthreads();
        #pragma unroll
        for (int q=0;q<4;q++){
            int p = tid + 256*q;
            int r = p>>4, kseg = p&15;
            int grow = min(rowbase + r, N_NODES-1);
            float4 v = *(const float4*)(x + (size_t)grow*F_IN + k0 + kseg*4);
            u16 h0=f2bf(v.x), h1v=f2bf(v.y), h2v=f2bf(v.z), h3v=f2bf(v.w);
            u16 e0=f2bf(v.x-bf2f(h0)), e1=f2bf(v.y-bf2f(h1v)),
                e2=f2bf(v.z-bf2f(h2v)), e3=f2bf(v.w-bf2f(h3v));
            int boff = (r*128 + kseg*8) ^ ((r&7)<<4);
            *(ushort4*)((char*)Ahi + boff) = make_ushort4(h0,h1v,h2v,h3v);
            *(ushort4*)((char*)Alo + boff) = make_ushort4(e0,e1,e2,e3);
        }
        __syncthreads();

        const int arow = wid*16 + lr;
        bf16x8 ahi[2], alo[2];
        #pragma unroll
        for (int kt=0;kt<2;kt++){
            int boff = (arow*128 + kt*64 + lq*16) ^ ((arow&7)<<4);
            ahi[kt] = *(const bf16x8*)((const char*)Ahi + boff);
            alo[kt] = *(const bf16x8*)((const char*)Alo + boff);
        }
        #pragma unroll
        for (int n=0;n<4;n++){
            #pragma unroll
            for (int kt=0;kt<2;kt++){
                const size_t wo = (size_t)(n*16+lr)*F_IN + k0 + kt*32 + lq*8;
                bf16x8 bhi = *(const bf16x8*)(whiT + wo);
                bf16x8 blo = *(const bf16x8*)(wloT + wo);
                acc[n] = __builtin_amdgcn_mfma_f32_16x16x32_bf16(ahi[kt], bhi, acc[n], 0,0,0);
                acc[n] = __builtin_amdgcn_mfma_f32_16x16x32_bf16(ahi[kt], blo, acc[n], 0,0,0);
                acc[n] = __builtin_amdgcn_mfma_f32_16x16x32_bf16(alo[kt], bhi, acc[n], 0,0,0);
            }
        }
    }

    // epilogue: C/D layout col=lane&15, row=(lane>>4)*4+i  [HW-verified]
    #pragma unroll
    for (int n=0;n<4;n++){
        int col = n*16 + lr;
        float as_w = att_src[col], ad_w = att_dst[col];
        #pragma unroll
        for (int i=0;i<4;i++){
            int node = rowbase + wid*16 + lq*4 + i;
            float v = acc[n][i];
            float s = v*as_w, d = v*ad_w;
            s += __shfl_xor(s,1); d += __shfl_xor(d,1);
            s += __shfl_xor(s,2); d += __shfl_xor(d,2);
            s += __shfl_xor(s,4); d += __shfl_xor(d,4);
            if (node < N_NODES){
                h1b[(size_t)node*D1 + col] = f2bf(v);
                if ((l&7)==0){
                    int head = col>>3;
                    asrc[node*H1 + head] = s;
                    adst[node*H1 + head] = d;
                }
            }
        }
    }
}

// ---------------------------------------------------------------- layer1 aggregation: 2 edges/iter, bf16 gather
__global__ __launch_bounds__(256) void k_agg1(
        const int* __restrict__ rowptr, const int* __restrict__ srcs,
        const float* __restrict__ asrc1, const float* __restrict__ adst1,
        const u16* __restrict__ h1b, float* __restrict__ out1){
    const int node = blockIdx.x*4 + (threadIdx.x>>6);
    const int lane = threadIdx.x & 63;
    const int half = lane >> 5;          // which edge of the pair
    const int cl   = lane & 31;          // channel-pair index (cols 2cl, 2cl+1)
    const int head = cl >> 2;
    const int r0 = __builtin_amdgcn_readfirstlane(rowptr[node]);
    const int r1 = __builtin_amdgcn_readfirstlane(rowptr[node+1]);
    const float ad = adst1[node*H1 + head];
    const u32* __restrict__ h1v = (const u32*)h1b;   // row stride 32 words
    float ax = 0.f, ay = 0.f, den = 0.f;
    for (int j=r0+half; j<r1; j+=2){
        int s = srcs[j];
        float w = __expf(leaky(asrc1[s*H1 + head] + ad));
        u32 pv = h1v[(size_t)s*32 + cl];
        ax += w * bf2f((u16)(pv & 0xFFFFu));
        ay += w * bf2f((u16)(pv >> 16));
        den += w;
    }
    ax += __shfl_xor(ax, 32);
    ay += __shfl_xor(ay, 32);
    den += __shfl_xor(den, 32);
    if (half == 0){
        float inv = 1.f/den;
        *(float2*)&out1[(size_t)node*D1 + cl*2] = make_float2(ax*inv, ay*inv);
    }
}

// ---------------------------------------------------------------- GEMM2 via MFMA: h2 = elu(out1+b1) @ W2 (+alpha epilogue); h2 stored bf16
__global__ __launch_bounds__(256) void k_gemm2(
        const float* __restrict__ out1, const float* __restrict__ b1,
        const u16* __restrict__ w2hiT, const u16* __restrict__ w2loT,
        const float* __restrict__ att_src2, const float* __restrict__ att_dst2,
        u16* __restrict__ h2b, float* __restrict__ asrc2, float* __restrict__ adst2){
    __shared__ u16 Ahi[64*64];   // 8 KB, XOR-swizzled
    __shared__ u16 Alo[64*64];   // 8 KB
    const int tid = threadIdx.x;
    const int wid = tid>>6, l = tid&63;
    const int lq = l>>4, lr = l&15;
    const int rowbase = blockIdx.x*64;

    #pragma unroll
    for (int q=0;q<4;q++){
        int p = tid + 256*q;
        int r = p>>4, kseg = p&15;
        int grow = min(rowbase + r, N_NODES-1);
        float4 v = *(const float4*)(out1 + (size_t)grow*D1 + kseg*4);
        float4 bb = *(const float4*)(b1 + kseg*4);
        float a0 = v.x+bb.x, a1 = v.y+bb.y, a2 = v.z+bb.z, a3 = v.w+bb.w;
        a0 = a0>0.f ? a0 : (__expf(a0)-1.f);
        a1 = a1>0.f ? a1 : (__expf(a1)-1.f);
        a2 = a2>0.f ? a2 : (__expf(a2)-1.f);
        a3 = a3>0.f ? a3 : (__expf(a3)-1.f);
        u16 h0=f2bf(a0), h1v=f2bf(a1), h2v=f2bf(a2), h3v=f2bf(a3);
        u16 e0=f2bf(a0-bf2f(h0)), e1=f2bf(a1-bf2f(h1v)),
            e2=f2bf(a2-bf2f(h2v)), e3=f2bf(a3-bf2f(h3v));
        int boff = (r*128 + kseg*8) ^ ((r&7)<<4);
        *(ushort4*)((char*)Ahi + boff) = make_ushort4(h0,h1v,h2v,h3v);
        *(ushort4*)((char*)Alo + boff) = make_ushort4(e0,e1,e2,e3);
    }
    __syncthreads();

    const int arow = wid*16 + lr;
    bf16x8 ahi[2], alo[2];
    #pragma unroll
    for (int kt=0;kt<2;kt++){
        int boff = (arow*128 + kt*64 + lq*16) ^ ((arow&7)<<4);
        ahi[kt] = *(const bf16x8*)((const char*)Ahi + boff);
        alo[kt] = *(const bf16x8*)((const char*)Alo + boff);
    }

    f32x4 acc[8];
    #pragma unroll
    for (int n=0;n<8;n++) acc[n] = (f32x4){0.f,0.f,0.f,0.f};
    #pragma unroll
    for (int n=0;n<8;n++){
        #pragma unroll
        for (int kt=0;kt<2;kt++){
            const size_t wo = (size_t)(n*16+lr)*D1 + kt*32 + lq*8;
            bf16x8 bhi = *(const bf16x8*)(w2hiT + wo);
            bf16x8 blo = *(const bf16x8*)(w2loT + wo);
            acc[n] = __builtin_amdgcn_mfma_f32_16x16x32_bf16(ahi[kt], bhi, acc[n], 0,0,0);
            acc[n] = __builtin_amdgcn_mfma_f32_16x16x32_bf16(ahi[kt], blo, acc[n], 0,0,0);
            acc[n] = __builtin_amdgcn_mfma_f32_16x16x32_bf16(alo[kt], bhi, acc[n], 0,0,0);
        }
    }

    float aw[8], dw[8];
    #pragma unroll
    for (int n=0;n<8;n++){ aw[n]=att_src2[n*16+lr]; dw[n]=att_dst2[n*16+lr]; }
    #pragma unroll
    for (int i=0;i<4;i++){
        int node = rowbase + wid*16 + lq*4 + i;
        bool ok = node < N_NODES;
        float s = 0.f, d = 0.f;
        #pragma unroll
        for (int n=0;n<8;n++){
            float v = acc[n][i];
            s = fmaf(v, aw[n], s);
            d = fmaf(v, dw[n], d);
            if (ok) h2b[(size_t)node*OUT_C + n*16 + lr] = f2bf(v);
        }
        s += __shfl_xor(s,1); d += __shfl_xor(d,1);
        s += __shfl_xor(s,2); d += __shfl_xor(d,2);
        s += __shfl_xor(s,4); d += __shfl_xor(d,4);
        s += __shfl_xor(s,8); d += __shfl_xor(d,8);
        if (ok && lr==0){ asrc2[node]=s; adst2[node]=d; }
    }
}

// ---------------------------------------------------------------- layer2 aggregation (bf16 gather, u32/lane)
__global__ __launch_bounds__(256) void k_agg2(
        const int* __restrict__ rowptr, const int* __restrict__ srcs,
        const float* __restrict__ asrc2, const float* __restrict__ adst2,
        const u16* __restrict__ h2b, const float* __restrict__ b2,
        float* __restrict__ out){
    const int node = blockIdx.x*4 + (threadIdx.x>>6);
    const int lane = threadIdx.x & 63;
    const int r0 = __builtin_amdgcn_readfirstlane(rowptr[node]);
    const int r1 = __builtin_amdgcn_readfirstlane(rowptr[node+1]);
    const float ad = adst2[node];
    const u32* __restrict__ h2v = (const u32*)h2b;   // row stride 64 words
    float ax = 0.f, ay = 0.f, den = 0.f;
    #pragma unroll 4
    for (int j=r0; j<r1; j++){
        int s = __builtin_amdgcn_readfirstlane(srcs[j]);
        float w = __expf(leaky(asrc2[s] + ad));
        u32 pv = h2v[(size_t)s*64 + lane];
        ax += w * bf2f((u16)(pv & 0xFFFFu));
        ay += w * bf2f((u16)(pv >> 16));
        den += w;
    }
    float inv = 1.f/den;
    float2 bb = ((const float2*)b2)[lane];
    float2 o; o.x = ax*inv + bb.x; o.y = ay*inv + bb.y;
    *(float2*)&out[(size_t)node*OUT_C + lane*2] = o;
}

// ---------------------------------------------------------------- launch
extern "C" void kernel_launch(void* const* d_in, const int* in_sizes, int n_in,
                              void* d_out, int out_size, void* d_ws, size_t ws_size,
                              hipStream_t stream) {
    const float* x        = (const float*)d_in[0];
    const int*   edge     = (const int*)  d_in[1];
    const float* W1       = (const float*)d_in[2];
    const float* att_src1 = (const float*)d_in[3];
    const float* att_dst1 = (const float*)d_in[4];
    const float* b1       = (const float*)d_in[5];
    const float* W2       = (const float*)d_in[6];
    const float* att_src2 = (const float*)d_in[7];
    const float* att_dst2 = (const float*)d_in[8];
    const float* b2       = (const float*)d_in[9];
    float* out = (float*)d_out;

    const int E  = in_sizes[1] / 2;
    const int ET = E + N_NODES;
    const int CE = (ET + NHB - 1) / NHB;
    const int* src_a = edge;
    const int* dst_a = edge + E;

    // workspace layout (element counts sized for f32 regions; h1/h2 use half as u16)
    float* ws = (float*)d_ws;
    float* h1f   = ws;                            // N*64 f32 region -> used as u16 h1b
    float* asrc1 = h1f   + (size_t)N_NODES*D1;    // N*8
    float* adst1 = asrc1 + (size_t)N_NODES*H1;    // N*8
    float* out1  = adst1 + (size_t)N_NODES*H1;    // N*64
    float* h2f   = out1  + (size_t)N_NODES*D1;    // N*128 f32 region -> used as u16 h2b
    float* asrc2 = h2f   + (size_t)N_NODES*OUT_C; // N
    float* adst2 = asrc2 + N_NODES;               // N
    int*   cnt    = (int*)(adst2 + N_NODES);      // N
    int*   rowptr = cnt    + N_NODES;             // N+4
    int*   srcs   = rowptr + (N_NODES+4);         // ET
    int*   bsum   = srcs   + ET;                  // 256
    int*   boff   = bsum   + 256;                 // 256
    u32*   histmat= (u32*)(boff + 256);           // NHB*N (51.2 MB; dead after scatterB)
    u16*   whiT   = (u16*)histmat;                // overlays histmat
    u16*   wloT   = whiT + F_IN*D1;
    u16*   w2hiT  = wloT + F_IN*D1;
    u16*   w2loT  = w2hiT + D1*OUT_C;
    u16*   h1b    = (u16*)h1f;
    u16*   h2b    = (u16*)h2f;

    // ---- CSR build (atomic-free counting sort)
    hipLaunchKernelGGL(k_histB,   dim3(NHB), dim3(HTHREADS), 0, stream, dst_a, E, CE, histmat);
    hipLaunchKernelGGL(k_colscan, dim3(SNBLK), dim3(256), 0, stream, histmat, cnt);
    hipLaunchKernelGGL(k_scanA,   dim3(SNBLK), dim3(256), 0, stream, cnt, bsum);
    hipLaunchKernelGGL(k_scanB,   dim3(1), dim3(256), 0, stream, bsum, boff, rowptr);
    hipLaunchKernelGGL(k_scanC,   dim3(SNBLK), dim3(256), 0, stream, cnt, boff, rowptr);
    hipLaunchKernelGGL(k_scatterB,dim3(NHB), dim3(HTHREADS), 0, stream,
                       src_a, dst_a, E, CE, histmat, rowptr, srcs);

    // ---- weight prep (histmat dead after scatterB)
    hipLaunchKernelGGL(k_cvtW2, dim3((D1*OUT_C+255)/256), dim3(256), 0, stream,
                       W2, w2hiT, w2loT);
    hipLaunchKernelGGL(k_cvtW, dim3((F_IN*D1+255)/256), dim3(256), 0, stream,
                       W1, whiT, wloT);

    // ---- layer 1
    hipLaunchKernelGGL(k_gemm1, dim3((N_NODES+63)/64), dim3(256), 0, stream,
                       x, whiT, wloT, att_src1, att_dst1, h1b, asrc1, adst1);
    hipLaunchKernelGGL(k_agg1, dim3(N_NODES/4), dim3(256), 0, stream,
                       rowptr, srcs, asrc1, adst1, h1b, out1);

    // ---- layer 2
    hipLaunchKernelGGL(k_gemm2, dim3((N_NODES+63)/64), dim3(256), 0, stream,
                       out1, b1, w2hiT, w2loT, att_src2, att_dst2, h2b, asrc2, adst2);
    hipLaunchKernelGGL(k_agg2, dim3(N_NODES/4), dim3(256), 0, stream,
                       rowptr, srcs, asrc2, adst2, h2b, b2, out);
}

// Round 10
// 355.061 us; speedup vs baseline: 1.5239x; 1.0674x over previous
//
#include <hip/hip_runtime.h>
#include <math.h>

#define N_NODES 50000
#define F_IN    512
#define H1      8
#define C1      8
#define D1      64    // H1*C1
#define OUT_C   128
#define NEG     0.2f

#define SCHUNK  256
#define SNBLK   ((N_NODES + SCHUNK - 1)/SCHUNK)   // 196

#define NHB      256    // histogram/scatter blocks
#define HTHREADS 1024
#define HALF     25000  // nodes per LDS pass
#define HWORDS   12500  // packed u32 words per pass (2 u16 counters each)

using bf16x8 = __attribute__((ext_vector_type(8))) short;
using f32x4  = __attribute__((ext_vector_type(4))) float;
typedef unsigned short u16;
typedef unsigned int   u32;

__device__ __forceinline__ float leaky(float x){
    return fmaxf(x, 0.f) + NEG * fminf(x, 0.f);
}
__device__ __forceinline__ u16 f2bf(float f){           // RNE
    u32 u = __float_as_uint(f);
    u32 r = u + 0x7FFF + ((u>>16)&1);
    return (u16)(r>>16);
}
__device__ __forceinline__ float bf2f(u16 h){ return __uint_as_float(((u32)h)<<16); }

// ---------------------------------------------------------------- per-block LDS histogram -> histmat[blk][node]
__global__ __launch_bounds__(1024) void k_histB(const int* __restrict__ dst_a, int E, int CE,
                                                u32* __restrict__ histmat){
    __shared__ u32 lcnt[HWORDS];
    const int blk = blockIdx.x;
    const int i0 = blk*CE;
    const int i1 = min(i0+CE, E + N_NODES);
    for (int p=0;p<2;p++){
        for (int w=threadIdx.x; w<HWORDS; w+=HTHREADS) lcnt[w]=0;
        __syncthreads();
        const int lo = p*HALF, hi = lo+HALF;
        for (int i=i0+(int)threadIdx.x; i<i1; i+=HTHREADS){
            int d = (i<E)? dst_a[i] : (i-E);
            if (d>=lo && d<hi){
                int dd = d - lo;
                atomicAdd(&lcnt[dd>>1], 1u<<((dd&1)*16));
            }
        }
        __syncthreads();
        uint2* dst = (uint2*)(histmat + (size_t)blk*N_NODES + lo);
        for (int w=threadIdx.x; w<HWORDS; w+=HTHREADS){
            u32 v = lcnt[w];
            dst[w] = make_uint2(v & 0xFFFFu, v >> 16);
        }
        __syncthreads();
    }
}

// ---------------------------------------------------------------- column scan: histmat -> per-block exclusive prefix, cnt
__global__ __launch_bounds__(256) void k_colscan(u32* __restrict__ histmat, int* __restrict__ cnt){
    int n = blockIdx.x*256 + threadIdx.x;
    if (n >= N_NODES) return;
    u32 run = 0;
    u32* p = histmat + n;
    #pragma unroll 4
    for (int b=0;b<NHB;b++){
        u32 v = p[(size_t)b*N_NODES];
        p[(size_t)b*N_NODES] = run;
        run += v;
    }
    cnt[n] = (int)run;
}

// ---------------------------------------------------------------- 3-phase scan over cnt -> rowptr
__global__ __launch_bounds__(256) void k_scanA(const int* __restrict__ cnt, int* bsum){
    __shared__ int sm[256];
    int idx = blockIdx.x*256 + threadIdx.x;
    int v = (idx < N_NODES) ? cnt[idx] : 0;
    sm[threadIdx.x] = v; __syncthreads();
    for (int off=128; off>0; off>>=1){
        if (threadIdx.x < off) sm[threadIdx.x] += sm[threadIdx.x+off];
        __syncthreads();
    }
    if (threadIdx.x==0) bsum[blockIdx.x] = sm[0];
}

__global__ __launch_bounds__(256) void k_scanB(const int* __restrict__ bsum, int* boff, int* rowptr){
    __shared__ int sm[256];
    int t = threadIdx.x;
    int v = (t < SNBLK) ? bsum[t] : 0;
    sm[t]=v; __syncthreads();
    for (int off=1; off<256; off<<=1){
        int u = (t>=off)? sm[t-off] : 0;
        __syncthreads();
        sm[t]+=u; __syncthreads();
    }
    if (t < SNBLK) boff[t] = sm[t] - v;       // exclusive
    if (t==255) rowptr[N_NODES] = sm[255];    // total = E + N
}

__global__ __launch_bounds__(256) void k_scanC(const int* __restrict__ cnt, const int* __restrict__ boff,
                                               int* rowptr){
    __shared__ int sm[256];
    int idx = blockIdx.x*256 + threadIdx.x;
    int t = threadIdx.x;
    int v = (idx<N_NODES)? cnt[idx] : 0;
    sm[t]=v; __syncthreads();
    for (int off=1; off<256; off<<=1){
        int u = (t>=off)? sm[t-off] : 0;
        __syncthreads();
        sm[t]+=u; __syncthreads();
    }
    if (idx<N_NODES){
        rowptr[idx] = boff[blockIdx.x] + sm[t] - v;
    }
}

// ---------------------------------------------------------------- atomic-free scatter (LDS local ranks)
__global__ __launch_bounds__(1024) void k_scatterB(const int* __restrict__ src_a, const int* __restrict__ dst_a,
                                                   int E, int CE,
                                                   const u32* __restrict__ histmat, const int* __restrict__ rowptr,
                                                   int* __restrict__ srcs){
    __shared__ u32 lcnt[HWORDS];
    const int blk = blockIdx.x;
    const int i0 = blk*CE;
    const int i1 = min(i0+CE, E + N_NODES);
    const u32* __restrict__ pb = histmat + (size_t)blk*N_NODES;
    for (int p=0;p<2;p++){
        for (int w=threadIdx.x; w<HWORDS; w+=HTHREADS) lcnt[w]=0;
        __syncthreads();
        const int lo = p*HALF, hi = lo+HALF;
        for (int i=i0+(int)threadIdx.x; i<i1; i+=HTHREADS){
            int s, d;
            if (i<E){ s=src_a[i]; d=dst_a[i]; } else { s=d=i-E; }
            if (d>=lo && d<hi){
                int dd = d - lo;
                u32 old = atomicAdd(&lcnt[dd>>1], 1u<<((dd&1)*16));
                u32 rank = (old >> ((dd&1)*16)) & 0xFFFFu;
                int pos = rowptr[d] + (int)pb[d] + (int)rank;
                srcs[pos] = s;
            }
        }
        __syncthreads();
    }
}

// ---------------------------------------------------------------- W1 split/transpose: whiT/wloT [64 col][512 k] bf16
__global__ void k_cvtW(const float* __restrict__ W1, u16* __restrict__ whiT, u16* __restrict__ wloT){
    int i = blockIdx.x*blockDim.x + threadIdx.x;   // 0..32767
    if (i >= F_IN*D1) return;
    int k = i >> 6, col = i & 63;
    float v = W1[i];
    u16 hi = f2bf(v);
    float lo = v - bf2f(hi);
    whiT[col*F_IN + k] = hi;
    wloT[col*F_IN + k] = f2bf(lo);
}

// ---------------------------------------------------------------- W2 split/transpose: [128 col][64 k] bf16
__global__ void k_cvtW2(const float* __restrict__ W2, u16* __restrict__ w2hiT, u16* __restrict__ w2loT){
    int i = blockIdx.x*blockDim.x + threadIdx.x;   // 0..8191
    if (i >= D1*OUT_C) return;
    int k = i >> 7, col = i & 127;
    float v = W2[i];
    u16 hi = f2bf(v);
    float lo = v - bf2f(hi);
    w2hiT[col*D1 + k] = hi;
    w2loT[col*D1 + k] = f2bf(lo);
}

// ---------------------------------------------------------------- GEMM1 via MFMA (split-bf16, f32-accurate); h1 stored bf16
__global__ __launch_bounds__(256) void k_gemm1(
        const float* __restrict__ x,
        const u16* __restrict__ whiT, const u16* __restrict__ wloT,
        const float* __restrict__ att_src, const float* __restrict__ att_dst,
        u16* __restrict__ h1b, float* __restrict__ asrc, float* __restrict__ adst){
    __shared__ u16 Ahi[64*64];   // 8 KB, XOR-swizzled [row][k]
    __shared__ u16 Alo[64*64];   // 8 KB
    const int tid = threadIdx.x;
    const int wid = tid>>6, l = tid&63;
    const int lq = l>>4, lr = l&15;
    const int rowbase = blockIdx.x*64;

    f32x4 acc[4];
    #pragma unroll
    for (int n=0;n<4;n++) acc[n] = (f32x4){0.f,0.f,0.f,0.f};

    for (int ks=0; ks<8; ks++){
        const int k0 = ks*64;
        __syncthreads();
        #pragma unroll
        for (int q=0;q<4;q++){
            int p = tid + 256*q;
            int r = p>>4, kseg = p&15;
            int grow = min(rowbase + r, N_NODES-1);
            float4 v = *(const float4*)(x + (size_t)grow*F_IN + k0 + kseg*4);
            u16 h0=f2bf(v.x), h1v=f2bf(v.y), h2v=f2bf(v.z), h3v=f2bf(v.w);
            u16 e0=f2bf(v.x-bf2f(h0)), e1=f2bf(v.y-bf2f(h1v)),
                e2=f2bf(v.z-bf2f(h2v)), e3=f2bf(v.w-bf2f(h3v));
            int boff = (r*128 + kseg*8) ^ ((r&7)<<4);
            *(ushort4*)((char*)Ahi + boff) = make_ushort4(h0,h1v,h2v,h3v);
            *(ushort4*)((char*)Alo + boff) = make_ushort4(e0,e1,e2,e3);
        }
        __syncthreads();

        const int arow = wid*16 + lr;
        bf16x8 ahi[2], alo[2];
        #pragma unroll
        for (int kt=0;kt<2;kt++){
            int boff = (arow*128 + kt*64 + lq*16) ^ ((arow&7)<<4);
            ahi[kt] = *(const bf16x8*)((const char*)Ahi + boff);
            alo[kt] = *(const bf16x8*)((const char*)Alo + boff);
        }
        #pragma unroll
        for (int n=0;n<4;n++){
            #pragma unroll
            for (int kt=0;kt<2;kt++){
                const size_t wo = (size_t)(n*16+lr)*F_IN + k0 + kt*32 + lq*8;
                bf16x8 bhi = *(const bf16x8*)(whiT + wo);
                bf16x8 blo = *(const bf16x8*)(wloT + wo);
                acc[n] = __builtin_amdgcn_mfma_f32_16x16x32_bf16(ahi[kt], bhi, acc[n], 0,0,0);
                acc[n] = __builtin_amdgcn_mfma_f32_16x16x32_bf16(ahi[kt], blo, acc[n], 0,0,0);
                acc[n] = __builtin_amdgcn_mfma_f32_16x16x32_bf16(alo[kt], bhi, acc[n], 0,0,0);
            }
        }
    }

    // epilogue: C/D layout col=lane&15, row=(lane>>4)*4+i  [HW-verified]
    #pragma unroll
    for (int n=0;n<4;n++){
        int col = n*16 + lr;
        float as_w = att_src[col], ad_w = att_dst[col];
        #pragma unroll
        for (int i=0;i<4;i++){
            int node = rowbase + wid*16 + lq*4 + i;
            float v = acc[n][i];
            float s = v*as_w, d = v*ad_w;
            s += __shfl_xor(s,1); d += __shfl_xor(d,1);
            s += __shfl_xor(s,2); d += __shfl_xor(d,2);
            s += __shfl_xor(s,4); d += __shfl_xor(d,4);
            if (node < N_NODES){
                h1b[(size_t)node*D1 + col] = f2bf(v);
                if ((l&7)==0){
                    int head = col>>3;
                    asrc[node*H1 + head] = s;
                    adst[node*H1 + head] = d;
                }
            }
        }
    }
}

// ---------------------------------------------------------------- layer1 aggregation: 2 waves/node, srcs batch-prefetch
__global__ __launch_bounds__(256) void k_agg1(
        const int* __restrict__ rowptr, const int* __restrict__ srcs,
        const float* __restrict__ asrc1, const float* __restrict__ adst1,
        const u16* __restrict__ h1b, float* __restrict__ out1){
    __shared__ float red[2][32][3];
    const int nloc = threadIdx.x >> 7;          // node within block (2/block)
    const int node = blockIdx.x*2 + nloc;
    const int wv   = (threadIdx.x >> 6) & 1;    // wave within node
    const int lane = threadIdx.x & 63;
    const int half = lane >> 5;                 // edge-substream within wave
    const int cl   = lane & 31;                 // channel-pair (cols 2cl, 2cl+1)
    const int head = cl >> 2;
    const int r0 = rowptr[node], r1 = rowptr[node+1];
    const int n  = r1 - r0;
    const int hn = (n + 1) >> 1;
    const int c0 = r0 + wv*hn;
    const int c1 = min(r1, c0 + hn);
    const float ad = adst1[node*H1 + head];
    const u32* __restrict__ h1v = (const u32*)h1b;   // row stride 32 words
    float ax = 0.f, ay = 0.f, den = 0.f;
    for (int base=c0; base<c1; base+=64){
        const int m = min(64, c1-base);
        int sl = srcs[(base+lane < c1) ? (base+lane) : (c1-1)];
        #pragma unroll 4
        for (int idx=half; idx<m; idx+=2){
            int s = __shfl(sl, idx);
            float w = __expf(leaky(asrc1[s*H1 + head] + ad));
            u32 pv = h1v[(size_t)s*32 + cl];
            ax += w * bf2f((u16)(pv & 0xFFFFu));
            ay += w * bf2f((u16)(pv >> 16));
            den += w;
        }
    }
    ax += __shfl_xor(ax, 32);
    ay += __shfl_xor(ay, 32);
    den += __shfl_xor(den, 32);
    if (wv==1 && lane < 32){
        red[nloc][cl][0]=ax; red[nloc][cl][1]=ay; red[nloc][cl][2]=den;
    }
    __syncthreads();
    if (wv==0 && lane < 32){
        ax  += red[nloc][cl][0];
        ay  += red[nloc][cl][1];
        den += red[nloc][cl][2];
        float inv = 1.f/den;
        *(float2*)&out1[(size_t)node*D1 + cl*2] = make_float2(ax*inv, ay*inv);
    }
}

// ---------------------------------------------------------------- GEMM2 via MFMA: h2 = elu(out1+b1) @ W2 (+alpha epilogue); h2 stored bf16
__global__ __launch_bounds__(256) void k_gemm2(
        const float* __restrict__ out1, const float* __restrict__ b1,
        const u16* __restrict__ w2hiT, const u16* __restrict__ w2loT,
        const float* __restrict__ att_src2, const float* __restrict__ att_dst2,
        u16* __restrict__ h2b, float* __restrict__ asrc2, float* __restrict__ adst2){
    __shared__ u16 Ahi[64*64];   // 8 KB, XOR-swizzled
    __shared__ u16 Alo[64*64];   // 8 KB
    const int tid = threadIdx.x;
    const int wid = tid>>6, l = tid&63;
    const int lq = l>>4, lr = l&15;
    const int rowbase = blockIdx.x*64;

    #pragma unroll
    for (int q=0;q<4;q++){
        int p = tid + 256*q;
        int r = p>>4, kseg = p&15;
        int grow = min(rowbase + r, N_NODES-1);
        float4 v = *(const float4*)(out1 + (size_t)grow*D1 + kseg*4);
        float4 bb = *(const float4*)(b1 + kseg*4);
        float a0 = v.x+bb.x, a1 = v.y+bb.y, a2 = v.z+bb.z, a3 = v.w+bb.w;
        a0 = a0>0.f ? a0 : (__expf(a0)-1.f);
        a1 = a1>0.f ? a1 : (__expf(a1)-1.f);
        a2 = a2>0.f ? a2 : (__expf(a2)-1.f);
        a3 = a3>0.f ? a3 : (__expf(a3)-1.f);
        u16 h0=f2bf(a0), h1v=f2bf(a1), h2v=f2bf(a2), h3v=f2bf(a3);
        u16 e0=f2bf(a0-bf2f(h0)), e1=f2bf(a1-bf2f(h1v)),
            e2=f2bf(a2-bf2f(h2v)), e3=f2bf(a3-bf2f(h3v));
        int boff = (r*128 + kseg*8) ^ ((r&7)<<4);
        *(ushort4*)((char*)Ahi + boff) = make_ushort4(h0,h1v,h2v,h3v);
        *(ushort4*)((char*)Alo + boff) = make_ushort4(e0,e1,e2,e3);
    }
    __syncthreads();

    const int arow = wid*16 + lr;
    bf16x8 ahi[2], alo[2];
    #pragma unroll
    for (int kt=0;kt<2;kt++){
        int boff = (arow*128 + kt*64 + lq*16) ^ ((arow&7)<<4);
        ahi[kt] = *(const bf16x8*)((const char*)Ahi + boff);
        alo[kt] = *(const bf16x8*)((const char*)Alo + boff);
    }

    f32x4 acc[8];
    #pragma unroll
    for (int n=0;n<8;n++) acc[n] = (f32x4){0.f,0.f,0.f,0.f};
    #pragma unroll
    for (int n=0;n<8;n++){
        #pragma unroll
        for (int kt=0;kt<2;kt++){
            const size_t wo = (size_t)(n*16+lr)*D1 + kt*32 + lq*8;
            bf16x8 bhi = *(const bf16x8*)(w2hiT + wo);
            bf16x8 blo = *(const bf16x8*)(w2loT + wo);
            acc[n] = __builtin_amdgcn_mfma_f32_16x16x32_bf16(ahi[kt], bhi, acc[n], 0,0,0);
            acc[n] = __builtin_amdgcn_mfma_f32_16x16x32_bf16(ahi[kt], blo, acc[n], 0,0,0);
            acc[n] = __builtin_amdgcn_mfma_f32_16x16x32_bf16(alo[kt], bhi, acc[n], 0,0,0);
        }
    }

    float aw[8], dw[8];
    #pragma unroll
    for (int n=0;n<8;n++){ aw[n]=att_src2[n*16+lr]; dw[n]=att_dst2[n*16+lr]; }
    #pragma unroll
    for (int i=0;i<4;i++){
        int node = rowbase + wid*16 + lq*4 + i;
        bool ok = node < N_NODES;
        float s = 0.f, d = 0.f;
        #pragma unroll
        for (int n=0;n<8;n++){
            float v = acc[n][i];
            s = fmaf(v, aw[n], s);
            d = fmaf(v, dw[n], d);
            if (ok) h2b[(size_t)node*OUT_C + n*16 + lr] = f2bf(v);
        }
        s += __shfl_xor(s,1); d += __shfl_xor(d,1);
        s += __shfl_xor(s,2); d += __shfl_xor(d,2);
        s += __shfl_xor(s,4); d += __shfl_xor(d,4);
        s += __shfl_xor(s,8); d += __shfl_xor(d,8);
        if (ok && lr==0){ asrc2[node]=s; adst2[node]=d; }
    }
}

// ---------------------------------------------------------------- layer2 aggregation: 2 waves/node, lane-parallel weights
__global__ __launch_bounds__(256) void k_agg2(
        const int* __restrict__ rowptr, const int* __restrict__ srcs,
        const float* __restrict__ asrc2, const float* __restrict__ adst2,
        const u16* __restrict__ h2b, const float* __restrict__ b2,
        float* __restrict__ out){
    __shared__ float red[2][64][3];
    const int nloc = threadIdx.x >> 7;          // node within block (2/block)
    const int node = blockIdx.x*2 + nloc;
    const int wv   = (threadIdx.x >> 6) & 1;    // wave within node
    const int lane = threadIdx.x & 63;
    const int r0 = rowptr[node], r1 = rowptr[node+1];
    const int n  = r1 - r0;
    const int hn = (n + 1) >> 1;
    const int c0 = r0 + wv*hn;
    const int c1 = min(r1, c0 + hn);
    const float ad = adst2[node];
    const u32* __restrict__ h2v = (const u32*)h2b;   // row stride 64 words
    float ax = 0.f, ay = 0.f, den = 0.f;
    for (int base=c0; base<c1; base+=64){
        const int m = min(64, c1-base);
        int eidx = base + lane;
        int sl = srcs[eidx < c1 ? eidx : (c1-1)];
        float wl = __expf(leaky(asrc2[sl] + ad));    // all 64 weights in parallel
        #pragma unroll 4
        for (int j=0; j<m; j++){
            int   s = __shfl(sl, j);
            float w = __shfl(wl, j);
            u32 pv = h2v[(size_t)s*64 + lane];
            ax += w * bf2f((u16)(pv & 0xFFFFu));
            ay += w * bf2f((u16)(pv >> 16));
            den += w;
        }
    }
    if (wv==1){
        red[nloc][lane][0]=ax; red[nloc][lane][1]=ay; red[nloc][lane][2]=den;
    }
    __syncthreads();
    if (wv==0){
        ax  += red[nloc][lane][0];
        ay  += red[nloc][lane][1];
        den += red[nloc][lane][2];
        float inv = 1.f/den;
        float2 bb = ((const float2*)b2)[lane];
        float2 o; o.x = ax*inv + bb.x; o.y = ay*inv + bb.y;
        *(float2*)&out[(size_t)node*OUT_C + lane*2] = o;
    }
}

// ---------------------------------------------------------------- launch
extern "C" void kernel_launch(void* const* d_in, const int* in_sizes, int n_in,
                              void* d_out, int out_size, void* d_ws, size_t ws_size,
                              hipStream_t stream) {
    const float* x        = (const float*)d_in[0];
    const int*   edge     = (const int*)  d_in[1];
    const float* W1       = (const float*)d_in[2];
    const float* att_src1 = (const float*)d_in[3];
    const float* att_dst1 = (const float*)d_in[4];
    const float* b1       = (const float*)d_in[5];
    const float* W2       = (const float*)d_in[6];
    const float* att_src2 = (const float*)d_in[7];
    const float* att_dst2 = (const float*)d_in[8];
    const float* b2       = (const float*)d_in[9];
    float* out = (float*)d_out;

    const int E  = in_sizes[1] / 2;
    const int ET = E + N_NODES;
    const int CE = (ET + NHB - 1) / NHB;
    const int* src_a = edge;
    const int* dst_a = edge + E;

    // workspace layout (element counts sized for f32 regions; h1/h2 use half as u16)
    float* ws = (float*)d_ws;
    float* h1f   = ws;                            // N*64 f32 region -> used as u16 h1b
    float* asrc1 = h1f   + (size_t)N_NODES*D1;    // N*8
    float* adst1 = asrc1 + (size_t)N_NODES*H1;    // N*8
    float* out1  = adst1 + (size_t)N_NODES*H1;    // N*64
    float* h2f   = out1  + (size_t)N_NODES*D1;    // N*128 f32 region -> used as u16 h2b
    float* asrc2 = h2f   + (size_t)N_NODES*OUT_C; // N
    float* adst2 = asrc2 + N_NODES;               // N
    int*   cnt    = (int*)(adst2 + N_NODES);      // N
    int*   rowptr = cnt    + N_NODES;             // N+4
    int*   srcs   = rowptr + (N_NODES+4);         // ET
    int*   bsum   = srcs   + ET;                  // 256
    int*   boff   = bsum   + 256;                 // 256
    u32*   histmat= (u32*)(boff + 256);           // NHB*N (51.2 MB; dead after scatterB)
    u16*   whiT   = (u16*)histmat;                // overlays histmat
    u16*   wloT   = whiT + F_IN*D1;
    u16*   w2hiT  = wloT + F_IN*D1;
    u16*   w2loT  = w2hiT + D1*OUT_C;
    u16*   h1b    = (u16*)h1f;
    u16*   h2b    = (u16*)h2f;

    // ---- CSR build (atomic-free counting sort)
    hipLaunchKernelGGL(k_histB,   dim3(NHB), dim3(HTHREADS), 0, stream, dst_a, E, CE, histmat);
    hipLaunchKernelGGL(k_colscan, dim3(SNBLK), dim3(256), 0, stream, histmat, cnt);
    hipLaunchKernelGGL(k_scanA,   dim3(SNBLK), dim3(256), 0, stream, cnt, bsum);
    hipLaunchKernelGGL(k_scanB,   dim3(1), dim3(256), 0, stream, bsum, boff, rowptr);
    hipLaunchKernelGGL(k_scanC,   dim3(SNBLK), dim3(256), 0, stream, cnt, boff, rowptr);
    hipLaunchKernelGGL(k_scatterB,dim3(NHB), dim3(HTHREADS), 0, stream,
                       src_a, dst_a, E, CE, histmat, rowptr, srcs);

    // ---- weight prep (histmat dead after scatterB)
    hipLaunchKernelGGL(k_cvtW2, dim3((D1*OUT_C+255)/256), dim3(256), 0, stream,
                       W2, w2hiT, w2loT);
    hipLaunchKernelGGL(k_cvtW, dim3((F_IN*D1+255)/256), dim3(256), 0, stream,
                       W1, whiT, wloT);

    // ---- layer 1
    hipLaunchKernelGGL(k_gemm1, dim3((N_NODES+63)/64), dim3(256), 0, stream,
                       x, whiT, wloT, att_src1, att_dst1, h1b, asrc1, adst1);
    hipLaunchKernelGGL(k_agg1, dim3(N_NODES/2), dim3(256), 0, stream,
                       rowptr, srcs, asrc1, adst1, h1b, out1);

    // ---- layer 2
    hipLaunchKernelGGL(k_gemm2, dim3((N_NODES+63)/64), dim3(256), 0, stream,
                       out1, b1, w2hiT, w2loT, att_src2, att_dst2, h2b, asrc2, adst2);
    hipLaunchKernelGGL(k_agg2, dim3(N_NODES/2), dim3(256), 0, stream,
                       rowptr, srcs, asrc2, adst2, h2b, b2, out);
}

// Round 11
// 282.500 us; speedup vs baseline: 1.9153x; 1.2569x over previous
//
#include <hip/hip_runtime.h>
#include <math.h>

#define N_NODES 50000
#define F_IN    512
#define H1      8
#define C1      8
#define D1      64    // H1*C1
#define OUT_C   128
#define NEG     0.2f

#define SCHUNK  256
#define SNBLK   ((N_NODES + SCHUNK - 1)/SCHUNK)   // 196

#define NHB      256    // histogram/scatter blocks
#define HTHREADS 1024
#define HALF     25000  // nodes per LDS pass
#define HWORDS   12500  // packed u32 words per pass (2 u16 counters each)

using bf16x8 = __attribute__((ext_vector_type(8))) short;
using f32x4  = __attribute__((ext_vector_type(4))) float;
typedef unsigned short u16;
typedef unsigned int   u32;

__device__ __forceinline__ float leaky(float x){
    return fmaxf(x, 0.f) + NEG * fminf(x, 0.f);
}
__device__ __forceinline__ u16 f2bf(float f){           // RNE
    u32 u = __float_as_uint(f);
    u32 r = u + 0x7FFF + ((u>>16)&1);
    return (u16)(r>>16);
}
__device__ __forceinline__ float bf2f(u16 h){ return __uint_as_float(((u32)h)<<16); }

// ---------------------------------------------------------------- per-block LDS histogram -> histmat[blk][node]
__global__ __launch_bounds__(1024) void k_histB(const int* __restrict__ dst_a, int E, int CE,
                                                u32* __restrict__ histmat){
    __shared__ u32 lcnt[HWORDS];
    const int blk = blockIdx.x;
    const int i0 = blk*CE;
    const int i1 = min(i0+CE, E + N_NODES);
    for (int p=0;p<2;p++){
        for (int w=threadIdx.x; w<HWORDS; w+=HTHREADS) lcnt[w]=0;
        __syncthreads();
        const int lo = p*HALF, hi = lo+HALF;
        for (int i=i0+(int)threadIdx.x; i<i1; i+=HTHREADS){
            int d = (i<E)? dst_a[i] : (i-E);
            if (d>=lo && d<hi){
                int dd = d - lo;
                atomicAdd(&lcnt[dd>>1], 1u<<((dd&1)*16));
            }
        }
        __syncthreads();
        uint2* dst = (uint2*)(histmat + (size_t)blk*N_NODES + lo);
        for (int w=threadIdx.x; w<HWORDS; w+=HTHREADS){
            u32 v = lcnt[w];
            dst[w] = make_uint2(v & 0xFFFFu, v >> 16);
        }
        __syncthreads();
    }
}

// ---------------------------------------------------------------- column scan: histmat -> per-block exclusive prefix, cnt
__global__ __launch_bounds__(256) void k_colscan(u32* __restrict__ histmat, int* __restrict__ cnt){
    int n = blockIdx.x*256 + threadIdx.x;
    if (n >= N_NODES) return;
    u32 run = 0;
    u32* p = histmat + n;
    #pragma unroll 4
    for (int b=0;b<NHB;b++){
        u32 v = p[(size_t)b*N_NODES];
        p[(size_t)b*N_NODES] = run;
        run += v;
    }
    cnt[n] = (int)run;
}

// ---------------------------------------------------------------- 3-phase scan over cnt -> rowptr
__global__ __launch_bounds__(256) void k_scanA(const int* __restrict__ cnt, int* bsum){
    __shared__ int sm[256];
    int idx = blockIdx.x*256 + threadIdx.x;
    int v = (idx < N_NODES) ? cnt[idx] : 0;
    sm[threadIdx.x] = v; __syncthreads();
    for (int off=128; off>0; off>>=1){
        if (threadIdx.x < off) sm[threadIdx.x] += sm[threadIdx.x+off];
        __syncthreads();
    }
    if (threadIdx.x==0) bsum[blockIdx.x] = sm[0];
}

__global__ __launch_bounds__(256) void k_scanB(const int* __restrict__ bsum, int* boff, int* rowptr){
    __shared__ int sm[256];
    int t = threadIdx.x;
    int v = (t < SNBLK) ? bsum[t] : 0;
    sm[t]=v; __syncthreads();
    for (int off=1; off<256; off<<=1){
        int u = (t>=off)? sm[t-off] : 0;
        __syncthreads();
        sm[t]+=u; __syncthreads();
    }
    if (t < SNBLK) boff[t] = sm[t] - v;       // exclusive
    if (t==255) rowptr[N_NODES] = sm[255];    // total = E + N
}

__global__ __launch_bounds__(256) void k_scanC(const int* __restrict__ cnt, const int* __restrict__ boff,
                                               int* rowptr){
    __shared__ int sm[256];
    int idx = blockIdx.x*256 + threadIdx.x;
    int t = threadIdx.x;
    int v = (idx<N_NODES)? cnt[idx] : 0;
    sm[t]=v; __syncthreads();
    for (int off=1; off<256; off<<=1){
        int u = (t>=off)? sm[t-off] : 0;
        __syncthreads();
        sm[t]+=u; __syncthreads();
    }
    if (idx<N_NODES){
        rowptr[idx] = boff[blockIdx.x] + sm[t] - v;
    }
}

// ---------------------------------------------------------------- atomic-free scatter (LDS local ranks)
__global__ __launch_bounds__(1024) void k_scatterB(const int* __restrict__ src_a, const int* __restrict__ dst_a,
                                                   int E, int CE,
                                                   const u32* __restrict__ histmat, const int* __restrict__ rowptr,
                                                   int* __restrict__ srcs){
    __shared__ u32 lcnt[HWORDS];
    const int blk = blockIdx.x;
    const int i0 = blk*CE;
    const int i1 = min(i0+CE, E + N_NODES);
    const u32* __restrict__ pb = histmat + (size_t)blk*N_NODES;
    for (int p=0;p<2;p++){
        for (int w=threadIdx.x; w<HWORDS; w+=HTHREADS) lcnt[w]=0;
        __syncthreads();
        const int lo = p*HALF, hi = lo+HALF;
        for (int i=i0+(int)threadIdx.x; i<i1; i+=HTHREADS){
            int s, d;
            if (i<E){ s=src_a[i]; d=dst_a[i]; } else { s=d=i-E; }
            if (d>=lo && d<hi){
                int dd = d - lo;
                u32 old = atomicAdd(&lcnt[dd>>1], 1u<<((dd&1)*16));
                u32 rank = (old >> ((dd&1)*16)) & 0xFFFFu;
                int pos = rowptr[d] + (int)pb[d] + (int)rank;
                srcs[pos] = s;
            }
        }
        __syncthreads();
    }
}

// ---------------------------------------------------------------- W1 split/transpose: whiT/wloT [64 col][512 k] bf16
__global__ void k_cvtW(const float* __restrict__ W1, u16* __restrict__ whiT, u16* __restrict__ wloT){
    int i = blockIdx.x*blockDim.x + threadIdx.x;   // 0..32767
    if (i >= F_IN*D1) return;
    int k = i >> 6, col = i & 63;
    float v = W1[i];
    u16 hi = f2bf(v);
    float lo = v - bf2f(hi);
    whiT[col*F_IN + k] = hi;
    wloT[col*F_IN + k] = f2bf(lo);
}

// ---------------------------------------------------------------- W2 split/transpose: [128 col][64 k] bf16
__global__ void k_cvtW2(const float* __restrict__ W2, u16* __restrict__ w2hiT, u16* __restrict__ w2loT){
    int i = blockIdx.x*blockDim.x + threadIdx.x;   // 0..8191
    if (i >= D1*OUT_C) return;
    int k = i >> 7, col = i & 127;
    float v = W2[i];
    u16 hi = f2bf(v);
    float lo = v - bf2f(hi);
    w2hiT[col*D1 + k] = hi;
    w2loT[col*D1 + k] = f2bf(lo);
}

// ---------------------------------------------------------------- GEMM1 via MFMA (split-bf16, f32-accurate); h1 stored bf16
__global__ __launch_bounds__(256) void k_gemm1(
        const float* __restrict__ x,
        const u16* __restrict__ whiT, const u16* __restrict__ wloT,
        const float* __restrict__ att_src, const float* __restrict__ att_dst,
        u16* __restrict__ h1b, float* __restrict__ asrc, float* __restrict__ adst){
    __shared__ u16 Ahi[64*64];   // 8 KB, XOR-swizzled [row][k]
    __shared__ u16 Alo[64*64];   // 8 KB
    const int tid = threadIdx.x;
    const int wid = tid>>6, l = tid&63;
    const int lq = l>>4, lr = l&15;
    const int rowbase = blockIdx.x*64;

    f32x4 acc[4];
    #pragma unroll
    for (int n=0;n<4;n++) acc[n] = (f32x4){0.f,0.f,0.f,0.f};

    for (int ks=0; ks<8; ks++){
        const int k0 = ks*64;
        __syncthreads();
        #pragma unroll
        for (int q=0;q<4;q++){
            int p = tid + 256*q;
            int r = p>>4, kseg = p&15;
            int grow = min(rowbase + r, N_NODES-1);
            float4 v = *(const float4*)(x + (size_t)grow*F_IN + k0 + kseg*4);
            u16 h0=f2bf(v.x), h1v=f2bf(v.y), h2v=f2bf(v.z), h3v=f2bf(v.w);
            u16 e0=f2bf(v.x-bf2f(h0)), e1=f2bf(v.y-bf2f(h1v)),
                e2=f2bf(v.z-bf2f(h2v)), e3=f2bf(v.w-bf2f(h3v));
            int boff = (r*128 + kseg*8) ^ ((r&7)<<4);
            *(ushort4*)((char*)Ahi + boff) = make_ushort4(h0,h1v,h2v,h3v);
            *(ushort4*)((char*)Alo + boff) = make_ushort4(e0,e1,e2,e3);
        }
        __syncthreads();

        const int arow = wid*16 + lr;
        bf16x8 ahi[2], alo[2];
        #pragma unroll
        for (int kt=0;kt<2;kt++){
            int boff = (arow*128 + kt*64 + lq*16) ^ ((arow&7)<<4);
            ahi[kt] = *(const bf16x8*)((const char*)Ahi + boff);
            alo[kt] = *(const bf16x8*)((const char*)Alo + boff);
        }
        #pragma unroll
        for (int n=0;n<4;n++){
            #pragma unroll
            for (int kt=0;kt<2;kt++){
                const size_t wo = (size_t)(n*16+lr)*F_IN + k0 + kt*32 + lq*8;
                bf16x8 bhi = *(const bf16x8*)(whiT + wo);
                bf16x8 blo = *(const bf16x8*)(wloT + wo);
                acc[n] = __builtin_amdgcn_mfma_f32_16x16x32_bf16(ahi[kt], bhi, acc[n], 0,0,0);
                acc[n] = __builtin_amdgcn_mfma_f32_16x16x32_bf16(ahi[kt], blo, acc[n], 0,0,0);
                acc[n] = __builtin_amdgcn_mfma_f32_16x16x32_bf16(alo[kt], bhi, acc[n], 0,0,0);
            }
        }
    }

    // epilogue: C/D layout col=lane&15, row=(lane>>4)*4+i  [HW-verified]
    #pragma unroll
    for (int n=0;n<4;n++){
        int col = n*16 + lr;
        float as_w = att_src[col], ad_w = att_dst[col];
        #pragma unroll
        for (int i=0;i<4;i++){
            int node = rowbase + wid*16 + lq*4 + i;
            float v = acc[n][i];
            float s = v*as_w, d = v*ad_w;
            s += __shfl_xor(s,1); d += __shfl_xor(d,1);
            s += __shfl_xor(s,2); d += __shfl_xor(d,2);
            s += __shfl_xor(s,4); d += __shfl_xor(d,4);
            if (node < N_NODES){
                h1b[(size_t)node*D1 + col] = f2bf(v);
                if ((l&7)==0){
                    int head = col>>3;
                    asrc[node*H1 + head] = s;
                    adst[node*H1 + head] = d;
                }
            }
        }
    }
}

// ---------------------------------------------------------------- layer1 aggregation: 8 edges per gather instruction
// lane = (g,p): g=lane>>3 edge slot, p=lane&7 head / channel block [8p,8p+8)
__global__ __launch_bounds__(256) void k_agg1(
        const int* __restrict__ rowptr, const int* __restrict__ srcs,
        const float* __restrict__ asrc1, const float* __restrict__ adst1,
        const u16* __restrict__ h1b, float* __restrict__ out1){
    const int node = blockIdx.x*4 + (threadIdx.x>>6);
    const int lane = threadIdx.x & 63;
    const int g = lane >> 3;
    const int p = lane & 7;
    const int r0 = __builtin_amdgcn_readfirstlane(rowptr[node]);
    const int r1 = __builtin_amdgcn_readfirstlane(rowptr[node+1]);
    const float ad = adst1[node*H1 + p];
    float a0=0,a1=0,a2=0,a3=0,a4=0,a5=0,a6=0,a7=0, den=0;
    for (int base=r0; base<r1; base+=64){
        int eidx = base + lane;
        int sl = srcs[eidx < r1 ? eidx : (r1-1)];
        const int m = min(64, r1-base);
        for (int k=0; k*8 < m; k++){
            int e = k*8 + g;
            int s = __shfl(sl, e);
            float w = (base + e < r1) ? __expf(leaky(asrc1[s*H1 + p] + ad)) : 0.f;
            uint4 pv = *(const uint4*)(h1b + (size_t)s*D1 + p*8);
            a0 += w*bf2f((u16)(pv.x&0xFFFFu)); a1 += w*bf2f((u16)(pv.x>>16));
            a2 += w*bf2f((u16)(pv.y&0xFFFFu)); a3 += w*bf2f((u16)(pv.y>>16));
            a4 += w*bf2f((u16)(pv.z&0xFFFFu)); a5 += w*bf2f((u16)(pv.z>>16));
            a6 += w*bf2f((u16)(pv.w&0xFFFFu)); a7 += w*bf2f((u16)(pv.w>>16));
            den += w;
        }
    }
    #pragma unroll
    for (int off=8; off<64; off<<=1){
        a0 += __shfl_xor(a0,off); a1 += __shfl_xor(a1,off);
        a2 += __shfl_xor(a2,off); a3 += __shfl_xor(a3,off);
        a4 += __shfl_xor(a4,off); a5 += __shfl_xor(a5,off);
        a6 += __shfl_xor(a6,off); a7 += __shfl_xor(a7,off);
        den += __shfl_xor(den,off);
    }
    if (g == 0){
        float inv = 1.f/den;
        float* o = out1 + (size_t)node*D1 + p*8;
        *(float4*)(o)   = make_float4(a0*inv, a1*inv, a2*inv, a3*inv);
        *(float4*)(o+4) = make_float4(a4*inv, a5*inv, a6*inv, a7*inv);
    }
}

// ---------------------------------------------------------------- GEMM2 via MFMA: h2 = elu(out1+b1) @ W2 (+alpha epilogue); h2 stored bf16
__global__ __launch_bounds__(256) void k_gemm2(
        const float* __restrict__ out1, const float* __restrict__ b1,
        const u16* __restrict__ w2hiT, const u16* __restrict__ w2loT,
        const float* __restrict__ att_src2, const float* __restrict__ att_dst2,
        u16* __restrict__ h2b, float* __restrict__ asrc2, float* __restrict__ adst2){
    __shared__ u16 Ahi[64*64];   // 8 KB, XOR-swizzled
    __shared__ u16 Alo[64*64];   // 8 KB
    const int tid = threadIdx.x;
    const int wid = tid>>6, l = tid&63;
    const int lq = l>>4, lr = l&15;
    const int rowbase = blockIdx.x*64;

    #pragma unroll
    for (int q=0;q<4;q++){
        int p = tid + 256*q;
        int r = p>>4, kseg = p&15;
        int grow = min(rowbase + r, N_NODES-1);
        float4 v = *(const float4*)(out1 + (size_t)grow*D1 + kseg*4);
        float4 bb = *(const float4*)(b1 + kseg*4);
        float a0 = v.x+bb.x, a1 = v.y+bb.y, a2 = v.z+bb.z, a3 = v.w+bb.w;
        a0 = a0>0.f ? a0 : (__expf(a0)-1.f);
        a1 = a1>0.f ? a1 : (__expf(a1)-1.f);
        a2 = a2>0.f ? a2 : (__expf(a2)-1.f);
        a3 = a3>0.f ? a3 : (__expf(a3)-1.f);
        u16 h0=f2bf(a0), h1v=f2bf(a1), h2v=f2bf(a2), h3v=f2bf(a3);
        u16 e0=f2bf(a0-bf2f(h0)), e1=f2bf(a1-bf2f(h1v)),
            e2=f2bf(a2-bf2f(h2v)), e3=f2bf(a3-bf2f(h3v));
        int boff = (r*128 + kseg*8) ^ ((r&7)<<4);
        *(ushort4*)((char*)Ahi + boff) = make_ushort4(h0,h1v,h2v,h3v);
        *(ushort4*)((char*)Alo + boff) = make_ushort4(e0,e1,e2,e3);
    }
    __syncthreads();

    const int arow = wid*16 + lr;
    bf16x8 ahi[2], alo[2];
    #pragma unroll
    for (int kt=0;kt<2;kt++){
        int boff = (arow*128 + kt*64 + lq*16) ^ ((arow&7)<<4);
        ahi[kt] = *(const bf16x8*)((const char*)Ahi + boff);
        alo[kt] = *(const bf16x8*)((const char*)Alo + boff);
    }

    f32x4 acc[8];
    #pragma unroll
    for (int n=0;n<8;n++) acc[n] = (f32x4){0.f,0.f,0.f,0.f};
    #pragma unroll
    for (int n=0;n<8;n++){
        #pragma unroll
        for (int kt=0;kt<2;kt++){
            const size_t wo = (size_t)(n*16+lr)*D1 + kt*32 + lq*8;
            bf16x8 bhi = *(const bf16x8*)(w2hiT + wo);
            bf16x8 blo = *(const bf16x8*)(w2loT + wo);
            acc[n] = __builtin_amdgcn_mfma_f32_16x16x32_bf16(ahi[kt], bhi, acc[n], 0,0,0);
            acc[n] = __builtin_amdgcn_mfma_f32_16x16x32_bf16(ahi[kt], blo, acc[n], 0,0,0);
            acc[n] = __builtin_amdgcn_mfma_f32_16x16x32_bf16(alo[kt], bhi, acc[n], 0,0,0);
        }
    }

    float aw[8], dw[8];
    #pragma unroll
    for (int n=0;n<8;n++){ aw[n]=att_src2[n*16+lr]; dw[n]=att_dst2[n*16+lr]; }
    #pragma unroll
    for (int i=0;i<4;i++){
        int node = rowbase + wid*16 + lq*4 + i;
        bool ok = node < N_NODES;
        float s = 0.f, d = 0.f;
        #pragma unroll
        for (int n=0;n<8;n++){
            float v = acc[n][i];
            s = fmaf(v, aw[n], s);
            d = fmaf(v, dw[n], d);
            if (ok) h2b[(size_t)node*OUT_C + n*16 + lr] = f2bf(v);
        }
        s += __shfl_xor(s,1); d += __shfl_xor(d,1);
        s += __shfl_xor(s,2); d += __shfl_xor(d,2);
        s += __shfl_xor(s,4); d += __shfl_xor(d,4);
        s += __shfl_xor(s,8); d += __shfl_xor(d,8);
        if (ok && lr==0){ asrc2[node]=s; adst2[node]=d; }
    }
}

// ---------------------------------------------------------------- layer2 aggregation: 4 edges per gather instruction
// lane = (g,p): g=lane>>4 edge slot, p=lane&15 channel block [8p,8p+8)
__global__ __launch_bounds__(256) void k_agg2(
        const int* __restrict__ rowptr, const int* __restrict__ srcs,
        const float* __restrict__ asrc2, const float* __restrict__ adst2,
        const u16* __restrict__ h2b, const float* __restrict__ b2,
        float* __restrict__ out){
    const int node = blockIdx.x*4 + (threadIdx.x>>6);
    const int lane = threadIdx.x & 63;
    const int g = lane >> 4;
    const int p = lane & 15;
    const int r0 = __builtin_amdgcn_readfirstlane(rowptr[node]);
    const int r1 = __builtin_amdgcn_readfirstlane(rowptr[node+1]);
    const float ad = adst2[node];
    float a0=0,a1=0,a2=0,a3=0,a4=0,a5=0,a6=0,a7=0, den=0;
    for (int base=r0; base<r1; base+=64){
        int eidx = base + lane;
        int sl = srcs[eidx < r1 ? eidx : (r1-1)];
        float wl = (eidx < r1) ? __expf(leaky(asrc2[sl] + ad)) : 0.f;
        const int m = min(64, r1-base);
        for (int k=0; k*4 < m; k++){
            int e = k*4 + g;
            int   s = __shfl(sl, e);
            float w = __shfl(wl, e);      // 0 for padded slots
            uint4 pv = *(const uint4*)(h2b + (size_t)s*OUT_C + p*8);
            a0 += w*bf2f((u16)(pv.x&0xFFFFu)); a1 += w*bf2f((u16)(pv.x>>16));
            a2 += w*bf2f((u16)(pv.y&0xFFFFu)); a3 += w*bf2f((u16)(pv.y>>16));
            a4 += w*bf2f((u16)(pv.z&0xFFFFu)); a5 += w*bf2f((u16)(pv.z>>16));
            a6 += w*bf2f((u16)(pv.w&0xFFFFu)); a7 += w*bf2f((u16)(pv.w>>16));
            den += w;
        }
    }
    #pragma unroll
    for (int off=16; off<64; off<<=1){
        a0 += __shfl_xor(a0,off); a1 += __shfl_xor(a1,off);
        a2 += __shfl_xor(a2,off); a3 += __shfl_xor(a3,off);
        a4 += __shfl_xor(a4,off); a5 += __shfl_xor(a5,off);
        a6 += __shfl_xor(a6,off); a7 += __shfl_xor(a7,off);
        den += __shfl_xor(den,off);
    }
    if (g == 0){
        float inv = 1.f/den;
        const float* bb = b2 + p*8;
        float* o = out + (size_t)node*OUT_C + p*8;
        *(float4*)(o)   = make_float4(a0*inv+bb[0], a1*inv+bb[1], a2*inv+bb[2], a3*inv+bb[3]);
        *(float4*)(o+4) = make_float4(a4*inv+bb[4], a5*inv+bb[5], a6*inv+bb[6], a7*inv+bb[7]);
    }
}

// ---------------------------------------------------------------- launch
extern "C" void kernel_launch(void* const* d_in, const int* in_sizes, int n_in,
                              void* d_out, int out_size, void* d_ws, size_t ws_size,
                              hipStream_t stream) {
    const float* x        = (const float*)d_in[0];
    const int*   edge     = (const int*)  d_in[1];
    const float* W1       = (const float*)d_in[2];
    const float* att_src1 = (const float*)d_in[3];
    const float* att_dst1 = (const float*)d_in[4];
    const float* b1       = (const float*)d_in[5];
    const float* W2       = (const float*)d_in[6];
    const float* att_src2 = (const float*)d_in[7];
    const float* att_dst2 = (const float*)d_in[8];
    const float* b2       = (const float*)d_in[9];
    float* out = (float*)d_out;

    const int E  = in_sizes[1] / 2;
    const int ET = E + N_NODES;
    const int CE = (ET + NHB - 1) / NHB;
    const int* src_a = edge;
    const int* dst_a = edge + E;

    // workspace layout (element counts sized for f32 regions; h1/h2 use half as u16)
    float* ws = (float*)d_ws;
    float* h1f   = ws;                            // N*64 f32 region -> used as u16 h1b
    float* asrc1 = h1f   + (size_t)N_NODES*D1;    // N*8
    float* adst1 = asrc1 + (size_t)N_NODES*H1;    // N*8
    float* out1  = adst1 + (size_t)N_NODES*H1;    // N*64
    float* h2f   = out1  + (size_t)N_NODES*D1;    // N*128 f32 region -> used as u16 h2b
    float* asrc2 = h2f   + (size_t)N_NODES*OUT_C; // N
    float* adst2 = asrc2 + N_NODES;               // N
    int*   cnt    = (int*)(adst2 + N_NODES);      // N
    int*   rowptr = cnt    + N_NODES;             // N+4
    int*   srcs   = rowptr + (N_NODES+4);         // ET
    int*   bsum   = srcs   + ET;                  // 256
    int*   boff   = bsum   + 256;                 // 256
    u32*   histmat= (u32*)(boff + 256);           // NHB*N (51.2 MB; dead after scatterB)
    u16*   whiT   = (u16*)histmat;                // overlays histmat
    u16*   wloT   = whiT + F_IN*D1;
    u16*   w2hiT  = wloT + F_IN*D1;
    u16*   w2loT  = w2hiT + D1*OUT_C;
    u16*   h1b    = (u16*)h1f;
    u16*   h2b    = (u16*)h2f;

    // ---- CSR build (atomic-free counting sort)
    hipLaunchKernelGGL(k_histB,   dim3(NHB), dim3(HTHREADS), 0, stream, dst_a, E, CE, histmat);
    hipLaunchKernelGGL(k_colscan, dim3(SNBLK), dim3(256), 0, stream, histmat, cnt);
    hipLaunchKernelGGL(k_scanA,   dim3(SNBLK), dim3(256), 0, stream, cnt, bsum);
    hipLaunchKernelGGL(k_scanB,   dim3(1), dim3(256), 0, stream, bsum, boff, rowptr);
    hipLaunchKernelGGL(k_scanC,   dim3(SNBLK), dim3(256), 0, stream, cnt, boff, rowptr);
    hipLaunchKernelGGL(k_scatterB,dim3(NHB), dim3(HTHREADS), 0, stream,
                       src_a, dst_a, E, CE, histmat, rowptr, srcs);

    // ---- weight prep (histmat dead after scatterB)
    hipLaunchKernelGGL(k_cvtW2, dim3((D1*OUT_C+255)/256), dim3(256), 0, stream,
                       W2, w2hiT, w2loT);
    hipLaunchKernelGGL(k_cvtW, dim3((F_IN*D1+255)/256), dim3(256), 0, stream,
                       W1, whiT, wloT);

    // ---- layer 1
    hipLaunchKernelGGL(k_gemm1, dim3((N_NODES+63)/64), dim3(256), 0, stream,
                       x, whiT, wloT, att_src1, att_dst1, h1b, asrc1, adst1);
    hipLaunchKernelGGL(k_agg1, dim3((N_NODES+3)/4), dim3(256), 0, stream,
                       rowptr, srcs, asrc1, adst1, h1b, out1);

    // ---- layer 2
    hipLaunchKernelGGL(k_gemm2, dim3((N_NODES+63)/64), dim3(256), 0, stream,
                       out1, b1, w2hiT, w2loT, att_src2, att_dst2, h2b, asrc2, adst2);
    hipLaunchKernelGGL(k_agg2, dim3((N_NODES+3)/4), dim3(256), 0, stream,
                       rowptr, srcs, asrc2, adst2, h2b, b2, out);
}

// Round 12
// 265.785 us; speedup vs baseline: 2.0358x; 1.0629x over previous
//
#include <hip/hip_runtime.h>
#include <math.h>

#define N_NODES 50000
#define F_IN    512
#define H1      8
#define C1      8
#define D1      64    // H1*C1
#define OUT_C   128
#define NEG     0.2f

#define SCHUNK  256
#define SNBLK   ((N_NODES + SCHUNK - 1)/SCHUNK)   // 196

#define NHB      256    // histogram/scatter blocks
#define HTHREADS 1024
#define HALF     25000  // nodes per LDS pass
#define HWORDS   12500  // packed u32 words per pass (2 u16 counters each)

using bf16x8 = __attribute__((ext_vector_type(8))) short;
using f32x4  = __attribute__((ext_vector_type(4))) float;
typedef unsigned short u16;
typedef unsigned int   u32;

__device__ __forceinline__ float leaky(float x){
    return fmaxf(x, 0.f) + NEG * fminf(x, 0.f);
}
__device__ __forceinline__ u16 f2bf(float f){           // RNE
    u32 u = __float_as_uint(f);
    u32 r = u + 0x7FFF + ((u>>16)&1);
    return (u16)(r>>16);
}
__device__ __forceinline__ float bf2f(u16 h){ return __uint_as_float(((u32)h)<<16); }

// ---------------------------------------------------------------- per-block LDS histogram -> histmat[blk][node] (u16)
__global__ __launch_bounds__(1024) void k_histB(const int* __restrict__ dst_a, int E, int CE,
                                                u16* __restrict__ histmat){
    __shared__ u32 lcnt[HWORDS];
    const int blk = blockIdx.x;
    const int i0 = blk*CE;
    const int i1 = min(i0+CE, E + N_NODES);
    for (int p=0;p<2;p++){
        for (int w=threadIdx.x; w<HWORDS; w+=HTHREADS) lcnt[w]=0;
        __syncthreads();
        const int lo = p*HALF, hi = lo+HALF;
        for (int i=i0+(int)threadIdx.x; i<i1; i+=HTHREADS){
            int d = (i<E)? dst_a[i] : (i-E);
            if (d>=lo && d<hi){
                int dd = d - lo;
                atomicAdd(&lcnt[dd>>1], 1u<<((dd&1)*16));
            }
        }
        __syncthreads();
        u16* dst = histmat + (size_t)blk*N_NODES + lo;
        for (int w=threadIdx.x; w<HWORDS; w+=HTHREADS){
            *(u32*)(dst + 2*w) = lcnt[w];   // lo u16 -> node 2w, hi u16 -> node 2w+1
        }
        __syncthreads();
    }
}

// ---------------------------------------------------------------- column scan: histmat -> per-block exclusive prefix (u16), cnt
__global__ __launch_bounds__(256) void k_colscan(u16* __restrict__ histmat, int* __restrict__ cnt){
    int n = blockIdx.x*256 + threadIdx.x;
    if (n >= N_NODES) return;
    u32 run = 0;
    u16* p = histmat + n;
    #pragma unroll 4
    for (int b=0;b<NHB;b++){
        u32 v = p[(size_t)b*N_NODES];
        p[(size_t)b*N_NODES] = (u16)run;
        run += v;
    }
    cnt[n] = (int)run;
}

// ---------------------------------------------------------------- 3-phase scan over cnt -> rowptr
__global__ __launch_bounds__(256) void k_scanA(const int* __restrict__ cnt, int* bsum){
    __shared__ int sm[256];
    int idx = blockIdx.x*256 + threadIdx.x;
    int v = (idx < N_NODES) ? cnt[idx] : 0;
    sm[threadIdx.x] = v; __syncthreads();
    for (int off=128; off>0; off>>=1){
        if (threadIdx.x < off) sm[threadIdx.x] += sm[threadIdx.x+off];
        __syncthreads();
    }
    if (threadIdx.x==0) bsum[blockIdx.x] = sm[0];
}

__global__ __launch_bounds__(256) void k_scanB(const int* __restrict__ bsum, int* boff, int* rowptr){
    __shared__ int sm[256];
    int t = threadIdx.x;
    int v = (t < SNBLK) ? bsum[t] : 0;
    sm[t]=v; __syncthreads();
    for (int off=1; off<256; off<<=1){
        int u = (t>=off)? sm[t-off] : 0;
        __syncthreads();
        sm[t]+=u; __syncthreads();
    }
    if (t < SNBLK) boff[t] = sm[t] - v;       // exclusive
    if (t==255) rowptr[N_NODES] = sm[255];    // total = E + N
}

__global__ __launch_bounds__(256) void k_scanC(const int* __restrict__ cnt, const int* __restrict__ boff,
                                               int* rowptr){
    __shared__ int sm[256];
    int idx = blockIdx.x*256 + threadIdx.x;
    int t = threadIdx.x;
    int v = (idx<N_NODES)? cnt[idx] : 0;
    sm[t]=v; __syncthreads();
    for (int off=1; off<256; off<<=1){
        int u = (t>=off)? sm[t-off] : 0;
        __syncthreads();
        sm[t]+=u; __syncthreads();
    }
    if (idx<N_NODES){
        rowptr[idx] = boff[blockIdx.x] + sm[t] - v;
    }
}

// ---------------------------------------------------------------- atomic-free scatter (LDS local ranks)
__global__ __launch_bounds__(1024) void k_scatterB(const int* __restrict__ src_a, const int* __restrict__ dst_a,
                                                   int E, int CE,
                                                   const u16* __restrict__ histmat, const int* __restrict__ rowptr,
                                                   int* __restrict__ srcs){
    __shared__ u32 lcnt[HWORDS];
    const int blk = blockIdx.x;
    const int i0 = blk*CE;
    const int i1 = min(i0+CE, E + N_NODES);
    const u16* __restrict__ pb = histmat + (size_t)blk*N_NODES;
    for (int p=0;p<2;p++){
        for (int w=threadIdx.x; w<HWORDS; w+=HTHREADS) lcnt[w]=0;
        __syncthreads();
        const int lo = p*HALF, hi = lo+HALF;
        for (int i=i0+(int)threadIdx.x; i<i1; i+=HTHREADS){
            int s, d;
            if (i<E){ s=src_a[i]; d=dst_a[i]; } else { s=d=i-E; }
            if (d>=lo && d<hi){
                int dd = d - lo;
                u32 old = atomicAdd(&lcnt[dd>>1], 1u<<((dd&1)*16));
                u32 rank = (old >> ((dd&1)*16)) & 0xFFFFu;
                int pos = rowptr[d] + (int)pb[d] + (int)rank;
                srcs[pos] = s;
            }
        }
        __syncthreads();
    }
}

// ---------------------------------------------------------------- W1 split/transpose: whiT/wloT [64 col][512 k] bf16
__global__ void k_cvtW(const float* __restrict__ W1, u16* __restrict__ whiT, u16* __restrict__ wloT){
    int i = blockIdx.x*blockDim.x + threadIdx.x;   // 0..32767
    if (i >= F_IN*D1) return;
    int k = i >> 6, col = i & 63;
    float v = W1[i];
    u16 hi = f2bf(v);
    float lo = v - bf2f(hi);
    whiT[col*F_IN + k] = hi;
    wloT[col*F_IN + k] = f2bf(lo);
}

// ---------------------------------------------------------------- W2 split/transpose: [128 col][64 k] bf16
__global__ void k_cvtW2(const float* __restrict__ W2, u16* __restrict__ w2hiT, u16* __restrict__ w2loT){
    int i = blockIdx.x*blockDim.x + threadIdx.x;   // 0..8191
    if (i >= D1*OUT_C) return;
    int k = i >> 7, col = i & 127;
    float v = W2[i];
    u16 hi = f2bf(v);
    float lo = v - bf2f(hi);
    w2hiT[col*D1 + k] = hi;
    w2loT[col*D1 + k] = f2bf(lo);
}

// ---------------------------------------------------------------- GEMM1 via MFMA (split-bf16), software-pipelined staging
__global__ __launch_bounds__(256) void k_gemm1(
        const float* __restrict__ x,
        const u16* __restrict__ whiT, const u16* __restrict__ wloT,
        const float* __restrict__ att_src, const float* __restrict__ att_dst,
        u16* __restrict__ h1b, float* __restrict__ asrc, float* __restrict__ adst){
    __shared__ u16 Ahi[64*64];   // 8 KB, XOR-swizzled [row][k]
    __shared__ u16 Alo[64*64];   // 8 KB
    const int tid = threadIdx.x;
    const int wid = tid>>6, l = tid&63;
    const int lq = l>>4, lr = l&15;
    const int rowbase = blockIdx.x*64;

    // staging coords (fixed per thread)
    int sboff[4];
    const float* xsrc[4];
    #pragma unroll
    for (int q=0;q<4;q++){
        int p = tid + 256*q;
        int r = p>>4, kseg = p&15;
        sboff[q] = (r*128 + kseg*8) ^ ((r&7)<<4);
        int grow = min(rowbase + r, N_NODES-1);
        xsrc[q] = x + (size_t)grow*F_IN + kseg*4;
    }

    // prologue: load K-step 0
    float4 xv[4];
    #pragma unroll
    for (int q=0;q<4;q++) xv[q] = *(const float4*)(xsrc[q]);

    f32x4 acc[4];
    #pragma unroll
    for (int n=0;n<4;n++) acc[n] = (f32x4){0.f,0.f,0.f,0.f};

    for (int ks=0; ks<8; ks++){
        // convert in-register tile (data loaded last iteration)
        ushort4 hi4[4], lo4[4];
        #pragma unroll
        for (int q=0;q<4;q++){
            float4 v = xv[q];
            u16 h0=f2bf(v.x), h1v=f2bf(v.y), h2v=f2bf(v.z), h3v=f2bf(v.w);
            hi4[q] = make_ushort4(h0,h1v,h2v,h3v);
            lo4[q] = make_ushort4(f2bf(v.x-bf2f(h0)), f2bf(v.y-bf2f(h1v)),
                                  f2bf(v.z-bf2f(h2v)), f2bf(v.w-bf2f(h3v)));
        }
        __syncthreads();   // previous step's LDS reads complete
        #pragma unroll
        for (int q=0;q<4;q++){
            *(ushort4*)((char*)Ahi + sboff[q]) = hi4[q];
            *(ushort4*)((char*)Alo + sboff[q]) = lo4[q];
        }
        __syncthreads();   // tile ready

        // issue next step's loads; latency hides under ds_read + MFMA below
        if (ks < 7){
            #pragma unroll
            for (int q=0;q<4;q++) xv[q] = *(const float4*)(xsrc[q] + (ks+1)*64);
        }

        const int k0 = ks*64;
        const int arow = wid*16 + lr;
        bf16x8 ahi[2], alo[2];
        #pragma unroll
        for (int kt=0;kt<2;kt++){
            int boff = (arow*128 + kt*64 + lq*16) ^ ((arow&7)<<4);
            ahi[kt] = *(const bf16x8*)((const char*)Ahi + boff);
            alo[kt] = *(const bf16x8*)((const char*)Alo + boff);
        }
        #pragma unroll
        for (int n=0;n<4;n++){
            #pragma unroll
            for (int kt=0;kt<2;kt++){
                const size_t wo = (size_t)(n*16+lr)*F_IN + k0 + kt*32 + lq*8;
                bf16x8 bhi = *(const bf16x8*)(whiT + wo);
                bf16x8 blo = *(const bf16x8*)(wloT + wo);
                acc[n] = __builtin_amdgcn_mfma_f32_16x16x32_bf16(ahi[kt], bhi, acc[n], 0,0,0);
                acc[n] = __builtin_amdgcn_mfma_f32_16x16x32_bf16(ahi[kt], blo, acc[n], 0,0,0);
                acc[n] = __builtin_amdgcn_mfma_f32_16x16x32_bf16(alo[kt], bhi, acc[n], 0,0,0);
            }
        }
    }

    // epilogue: C/D layout col=lane&15, row=(lane>>4)*4+i  [HW-verified]
    #pragma unroll
    for (int n=0;n<4;n++){
        int col = n*16 + lr;
        float as_w = att_src[col], ad_w = att_dst[col];
        #pragma unroll
        for (int i=0;i<4;i++){
            int node = rowbase + wid*16 + lq*4 + i;
            float v = acc[n][i];
            float s = v*as_w, d = v*ad_w;
            s += __shfl_xor(s,1); d += __shfl_xor(d,1);
            s += __shfl_xor(s,2); d += __shfl_xor(d,2);
            s += __shfl_xor(s,4); d += __shfl_xor(d,4);
            if (node < N_NODES){
                h1b[(size_t)node*D1 + col] = f2bf(v);
                if ((l&7)==0){
                    int head = col>>3;
                    asrc[node*H1 + head] = s;
                    adst[node*H1 + head] = d;
                }
            }
        }
    }
}

// ---------------------------------------------------------------- layer1 aggregation: 8 edges per gather instruction
__global__ __launch_bounds__(256) void k_agg1(
        const int* __restrict__ rowptr, const int* __restrict__ srcs,
        const float* __restrict__ asrc1, const float* __restrict__ adst1,
        const u16* __restrict__ h1b, float* __restrict__ out1){
    const int node = blockIdx.x*4 + (threadIdx.x>>6);
    const int lane = threadIdx.x & 63;
    const int g = lane >> 3;
    const int p = lane & 7;
    const int r0 = __builtin_amdgcn_readfirstlane(rowptr[node]);
    const int r1 = __builtin_amdgcn_readfirstlane(rowptr[node+1]);
    const float ad = adst1[node*H1 + p];
    float a0=0,a1=0,a2=0,a3=0,a4=0,a5=0,a6=0,a7=0, den=0;
    for (int base=r0; base<r1; base+=64){
        int eidx = base + lane;
        int sl = srcs[eidx < r1 ? eidx : (r1-1)];
        const int m = min(64, r1-base);
        for (int k=0; k*8 < m; k++){
            int e = k*8 + g;
            int s = __shfl(sl, e);
            float w = (base + e < r1) ? __expf(leaky(asrc1[s*H1 + p] + ad)) : 0.f;
            uint4 pv = *(const uint4*)(h1b + (size_t)s*D1 + p*8);
            a0 += w*bf2f((u16)(pv.x&0xFFFFu)); a1 += w*bf2f((u16)(pv.x>>16));
            a2 += w*bf2f((u16)(pv.y&0xFFFFu)); a3 += w*bf2f((u16)(pv.y>>16));
            a4 += w*bf2f((u16)(pv.z&0xFFFFu)); a5 += w*bf2f((u16)(pv.z>>16));
            a6 += w*bf2f((u16)(pv.w&0xFFFFu)); a7 += w*bf2f((u16)(pv.w>>16));
            den += w;
        }
    }
    #pragma unroll
    for (int off=8; off<64; off<<=1){
        a0 += __shfl_xor(a0,off); a1 += __shfl_xor(a1,off);
        a2 += __shfl_xor(a2,off); a3 += __shfl_xor(a3,off);
        a4 += __shfl_xor(a4,off); a5 += __shfl_xor(a5,off);
        a6 += __shfl_xor(a6,off); a7 += __shfl_xor(a7,off);
        den += __shfl_xor(den,off);
    }
    if (g == 0){
        float inv = 1.f/den;
        float* o = out1 + (size_t)node*D1 + p*8;
        *(float4*)(o)   = make_float4(a0*inv, a1*inv, a2*inv, a3*inv);
        *(float4*)(o+4) = make_float4(a4*inv, a5*inv, a6*inv, a7*inv);
    }
}

// ---------------------------------------------------------------- GEMM2 via MFMA: h2 = elu(out1+b1) @ W2 (+alpha epilogue); h2 stored bf16
__global__ __launch_bounds__(256) void k_gemm2(
        const float* __restrict__ out1, const float* __restrict__ b1,
        const u16* __restrict__ w2hiT, const u16* __restrict__ w2loT,
        const float* __restrict__ att_src2, const float* __restrict__ att_dst2,
        u16* __restrict__ h2b, float* __restrict__ asrc2, float* __restrict__ adst2){
    __shared__ u16 Ahi[64*64];   // 8 KB, XOR-swizzled
    __shared__ u16 Alo[64*64];   // 8 KB
    const int tid = threadIdx.x;
    const int wid = tid>>6, l = tid&63;
    const int lq = l>>4, lr = l&15;
    const int rowbase = blockIdx.x*64;

    #pragma unroll
    for (int q=0;q<4;q++){
        int p = tid + 256*q;
        int r = p>>4, kseg = p&15;
        int grow = min(rowbase + r, N_NODES-1);
        float4 v = *(const float4*)(out1 + (size_t)grow*D1 + kseg*4);
        float4 bb = *(const float4*)(b1 + kseg*4);
        float a0 = v.x+bb.x, a1 = v.y+bb.y, a2 = v.z+bb.z, a3 = v.w+bb.w;
        a0 = a0>0.f ? a0 : (__expf(a0)-1.f);
        a1 = a1>0.f ? a1 : (__expf(a1)-1.f);
        a2 = a2>0.f ? a2 : (__expf(a2)-1.f);
        a3 = a3>0.f ? a3 : (__expf(a3)-1.f);
        u16 h0=f2bf(a0), h1v=f2bf(a1), h2v=f2bf(a2), h3v=f2bf(a3);
        u16 e0=f2bf(a0-bf2f(h0)), e1=f2bf(a1-bf2f(h1v)),
            e2=f2bf(a2-bf2f(h2v)), e3=f2bf(a3-bf2f(h3v));
        int boff = (r*128 + kseg*8) ^ ((r&7)<<4);
        *(ushort4*)((char*)Ahi + boff) = make_ushort4(h0,h1v,h2v,h3v);
        *(ushort4*)((char*)Alo + boff) = make_ushort4(e0,e1,e2,e3);
    }
    __syncthreads();

    const int arow = wid*16 + lr;
    bf16x8 ahi[2], alo[2];
    #pragma unroll
    for (int kt=0;kt<2;kt++){
        int boff = (arow*128 + kt*64 + lq*16) ^ ((arow&7)<<4);
        ahi[kt] = *(const bf16x8*)((const char*)Ahi + boff);
        alo[kt] = *(const bf16x8*)((const char*)Alo + boff);
    }

    f32x4 acc[8];
    #pragma unroll
    for (int n=0;n<8;n++) acc[n] = (f32x4){0.f,0.f,0.f,0.f};
    #pragma unroll
    for (int n=0;n<8;n++){
        #pragma unroll
        for (int kt=0;kt<2;kt++){
            const size_t wo = (size_t)(n*16+lr)*D1 + kt*32 + lq*8;
            bf16x8 bhi = *(const bf16x8*)(w2hiT + wo);
            bf16x8 blo = *(const bf16x8*)(w2loT + wo);
            acc[n] = __builtin_amdgcn_mfma_f32_16x16x32_bf16(ahi[kt], bhi, acc[n], 0,0,0);
            acc[n] = __builtin_amdgcn_mfma_f32_16x16x32_bf16(ahi[kt], blo, acc[n], 0,0,0);
            acc[n] = __builtin_amdgcn_mfma_f32_16x16x32_bf16(alo[kt], bhi, acc[n], 0,0,0);
        }
    }

    float aw[8], dw[8];
    #pragma unroll
    for (int n=0;n<8;n++){ aw[n]=att_src2[n*16+lr]; dw[n]=att_dst2[n*16+lr]; }
    #pragma unroll
    for (int i=0;i<4;i++){
        int node = rowbase + wid*16 + lq*4 + i;
        bool ok = node < N_NODES;
        float s = 0.f, d = 0.f;
        #pragma unroll
        for (int n=0;n<8;n++){
            float v = acc[n][i];
            s = fmaf(v, aw[n], s);
            d = fmaf(v, dw[n], d);
            if (ok) h2b[(size_t)node*OUT_C + n*16 + lr] = f2bf(v);
        }
        s += __shfl_xor(s,1); d += __shfl_xor(d,1);
        s += __shfl_xor(s,2); d += __shfl_xor(d,2);
        s += __shfl_xor(s,4); d += __shfl_xor(d,4);
        s += __shfl_xor(s,8); d += __shfl_xor(d,8);
        if (ok && lr==0){ asrc2[node]=s; adst2[node]=d; }
    }
}

// ---------------------------------------------------------------- layer2 aggregation: 4 edges per gather instruction
__global__ __launch_bounds__(256) void k_agg2(
        const int* __restrict__ rowptr, const int* __restrict__ srcs,
        const float* __restrict__ asrc2, const float* __restrict__ adst2,
        const u16* __restrict__ h2b, const float* __restrict__ b2,
        float* __restrict__ out){
    const int node = blockIdx.x*4 + (threadIdx.x>>6);
    const int lane = threadIdx.x & 63;
    const int g = lane >> 4;
    const int p = lane & 15;
    const int r0 = __builtin_amdgcn_readfirstlane(rowptr[node]);
    const int r1 = __builtin_amdgcn_readfirstlane(rowptr[node+1]);
    const float ad = adst2[node];
    float a0=0,a1=0,a2=0,a3=0,a4=0,a5=0,a6=0,a7=0, den=0;
    for (int base=r0; base<r1; base+=64){
        int eidx = base + lane;
        int sl = srcs[eidx < r1 ? eidx : (r1-1)];
        float wl = (eidx < r1) ? __expf(leaky(asrc2[sl] + ad)) : 0.f;
        const int m = min(64, r1-base);
        for (int k=0; k*4 < m; k++){
            int e = k*4 + g;
            int   s = __shfl(sl, e);
            float w = __shfl(wl, e);      // 0 for padded slots
            uint4 pv = *(const uint4*)(h2b + (size_t)s*OUT_C + p*8);
            a0 += w*bf2f((u16)(pv.x&0xFFFFu)); a1 += w*bf2f((u16)(pv.x>>16));
            a2 += w*bf2f((u16)(pv.y&0xFFFFu)); a3 += w*bf2f((u16)(pv.y>>16));
            a4 += w*bf2f((u16)(pv.z&0xFFFFu)); a5 += w*bf2f((u16)(pv.z>>16));
            a6 += w*bf2f((u16)(pv.w&0xFFFFu)); a7 += w*bf2f((u16)(pv.w>>16));
            den += w;
        }
    }
    #pragma unroll
    for (int off=16; off<64; off<<=1){
        a0 += __shfl_xor(a0,off); a1 += __shfl_xor(a1,off);
        a2 += __shfl_xor(a2,off); a3 += __shfl_xor(a3,off);
        a4 += __shfl_xor(a4,off); a5 += __shfl_xor(a5,off);
        a6 += __shfl_xor(a6,off); a7 += __shfl_xor(a7,off);
        den += __shfl_xor(den,off);
    }
    if (g == 0){
        float inv = 1.f/den;
        const float* bb = b2 + p*8;
        float* o = out + (size_t)node*OUT_C + p*8;
        *(float4*)(o)   = make_float4(a0*inv+bb[0], a1*inv+bb[1], a2*inv+bb[2], a3*inv+bb[3]);
        *(float4*)(o+4) = make_float4(a4*inv+bb[4], a5*inv+bb[5], a6*inv+bb[6], a7*inv+bb[7]);
    }
}

// ---------------------------------------------------------------- launch
extern "C" void kernel_launch(void* const* d_in, const int* in_sizes, int n_in,
                              void* d_out, int out_size, void* d_ws, size_t ws_size,
                              hipStream_t stream) {
    const float* x        = (const float*)d_in[0];
    const int*   edge     = (const int*)  d_in[1];
    const float* W1       = (const float*)d_in[2];
    const float* att_src1 = (const float*)d_in[3];
    const float* att_dst1 = (const float*)d_in[4];
    const float* b1       = (const float*)d_in[5];
    const float* W2       = (const float*)d_in[6];
    const float* att_src2 = (const float*)d_in[7];
    const float* att_dst2 = (const float*)d_in[8];
    const float* b2       = (const float*)d_in[9];
    float* out = (float*)d_out;

    const int E  = in_sizes[1] / 2;
    const int ET = E + N_NODES;
    const int CE = (ET + NHB - 1) / NHB;
    const int* src_a = edge;
    const int* dst_a = edge + E;

    // workspace layout (element counts sized for f32 regions; h1/h2 use half as u16)
    float* ws = (float*)d_ws;
    float* h1f   = ws;                            // N*64 f32 region -> used as u16 h1b
    float* asrc1 = h1f   + (size_t)N_NODES*D1;    // N*8
    float* adst1 = asrc1 + (size_t)N_NODES*H1;    // N*8
    float* out1  = adst1 + (size_t)N_NODES*H1;    // N*64
    float* h2f   = out1  + (size_t)N_NODES*D1;    // N*128 f32 region -> used as u16 h2b
    float* asrc2 = h2f   + (size_t)N_NODES*OUT_C; // N
    float* adst2 = asrc2 + N_NODES;               // N
    int*   cnt    = (int*)(adst2 + N_NODES);      // N
    int*   rowptr = cnt    + N_NODES;             // N+4
    int*   srcs   = rowptr + (N_NODES+4);         // ET
    int*   bsum   = srcs   + ET;                  // 256
    int*   boff   = bsum   + 256;                 // 256
    u16*   histmat= (u16*)(boff + 256);           // NHB*N u16 (25.6 MB; dead after scatterB)
    u16*   whiT   = histmat;                      // overlays histmat
    u16*   wloT   = whiT + F_IN*D1;
    u16*   w2hiT  = wloT + F_IN*D1;
    u16*   w2loT  = w2hiT + D1*OUT_C;
    u16*   h1b    = (u16*)h1f;
    u16*   h2b    = (u16*)h2f;

    // ---- CSR build (atomic-free counting sort, u16 histmat)
    hipLaunchKernelGGL(k_histB,   dim3(NHB), dim3(HTHREADS), 0, stream, dst_a, E, CE, histmat);
    hipLaunchKernelGGL(k_colscan, dim3(SNBLK), dim3(256), 0, stream, histmat, cnt);
    hipLaunchKernelGGL(k_scanA,   dim3(SNBLK), dim3(256), 0, stream, cnt, bsum);
    hipLaunchKernelGGL(k_scanB,   dim3(1), dim3(256), 0, stream, bsum, boff, rowptr);
    hipLaunchKernelGGL(k_scanC,   dim3(SNBLK), dim3(256), 0, stream, cnt, boff, rowptr);
    hipLaunchKernelGGL(k_scatterB,dim3(NHB), dim3(HTHREADS), 0, stream,
                       src_a, dst_a, E, CE, histmat, rowptr, srcs);

    // ---- weight prep (histmat dead after scatterB)
    hipLaunchKernelGGL(k_cvtW2, dim3((D1*OUT_C+255)/256), dim3(256), 0, stream,
                       W2, w2hiT, w2loT);
    hipLaunchKernelGGL(k_cvtW, dim3((F_IN*D1+255)/256), dim3(256), 0, stream,
                       W1, whiT, wloT);

    // ---- layer 1
    hipLaunchKernelGGL(k_gemm1, dim3((N_NODES+63)/64), dim3(256), 0, stream,
                       x, whiT, wloT, att_src1, att_dst1, h1b, asrc1, adst1);
    hipLaunchKernelGGL(k_agg1, dim3((N_NODES+3)/4), dim3(256), 0, stream,
                       rowptr, srcs, asrc1, adst1, h1b, out1);

    // ---- layer 2
    hipLaunchKernelGGL(k_gemm2, dim3((N_NODES+63)/64), dim3(256), 0, stream,
                       out1, b1, w2hiT, w2loT, att_src2, att_dst2, h2b, asrc2, adst2);
    hipLaunchKernelGGL(k_agg2, dim3((N_NODES+3)/4), dim3(256), 0, stream,
                       rowptr, srcs, asrc2, adst2, h2b, b2, out);
}